// Round 2
// 1955.957 us; speedup vs baseline: 1.1090x; 1.1090x over previous
//
#include <hip/hip_runtime.h>

// ---------------------------------------------------------------------------
// Adaptive softmax (TransformerXL style), MI355X/gfx950.
// R=512 rows, buckets: n={20000,20000,160000,67735}, d={1024,256,64,16}.
// Pipeline: h->bf16 | Y_i = h P_i^T (MFMA) | cluster logits | logits GEMM
// (MFMA, writes raw logits + per-block softmax partials) | partial reduce |
// normalize | loss gather.
// ---------------------------------------------------------------------------

typedef __bf16 bf16x8 __attribute__((ext_vector_type(8)));
typedef float  f32x4  __attribute__((ext_vector_type(4)));

#define NEG_HUGE (-3.402823466e38f)

__device__ __forceinline__ unsigned short f2bf(float x) {
  unsigned int u = __float_as_uint(x);
  u = (u + 0x7fffu + ((u >> 16) & 1u)) >> 16;   // RNE
  return (unsigned short)u;
}
__device__ __forceinline__ float bf2f(unsigned short h) {
  return __uint_as_float(((unsigned int)h) << 16);
}
// merge two (max, sumexp) pairs; NEG_HUGE sentinel keeps this NaN-free
__device__ __forceinline__ void mergeMS(float& m, float& s, float mo, float so) {
  float mn = fmaxf(m, mo);
  s = s * expf(m - mn) + so * expf(mo - mn);
  m = mn;
}

// ---------------------------------------------------------------- h -> bf16
__global__ __launch_bounds__(256) void convert_h_kernel(
    const float* __restrict__ h, unsigned short* __restrict__ o) {
  int i = (blockIdx.x * 256 + threadIdx.x) * 4;          // 512 blocks, exact
  float4 v = *reinterpret_cast<const float4*>(h + i);
  uint2 u;
  u.x = (unsigned int)f2bf(v.x) | ((unsigned int)f2bf(v.y) << 16);
  u.y = (unsigned int)f2bf(v.z) | ((unsigned int)f2bf(v.w) << 16);
  *reinterpret_cast<uint2*>(o + i) = u;
}

// ---------------------------------------------------------------- GEMM
// C[512, N] = A_bf16[512, K] * B_f32[N, K]^T (+bias)
// SOFTMAX=true : store fp32 raw logits to outF (ld=ldo) + per-block (m,s)
// SOFTMAX=false: store bf16 to outH (ld=ldh)
constexpr int GBM = 64, GBN = 256, GBK = 64, GPK = GBK + 8;

template <bool SOFTMAX>
__global__ __launch_bounds__(256) void gemm_bt_kernel(
    const unsigned short* __restrict__ A, int lda, int K,
    const float* __restrict__ B, const float* __restrict__ bias, int N,
    float* __restrict__ outF, long long ldo,
    unsigned short* __restrict__ outH, int ldh,
    float* __restrict__ partials, int nChunks) {
  __shared__ unsigned short As[GBM][GPK];   // +8 pad keeps b128 align, spreads banks
  __shared__ unsigned short Bs[GBN][GPK];
  __shared__ float red[GBM][4][2];

  const int tid = threadIdx.x;
  const int lane = tid & 63, w = tid >> 6;
  const int q = lane >> 4, l15 = lane & 15;
  const int row0 = blockIdx.x * GBM;
  const int colBase = blockIdx.y * GBN;

  f32x4 acc[4][4];
#pragma unroll
  for (int i = 0; i < 4; ++i)
#pragma unroll
    for (int j = 0; j < 4; ++j) acc[i][j] = (f32x4){0.f, 0.f, 0.f, 0.f};

  for (int k0 = 0; k0 < K; k0 += GBK) {
    __syncthreads();
    // stage A: 64 rows x 64 k bf16 (16B per thread-iter, 2 iters)
#pragma unroll
    for (int i = 0; i < 2; ++i) {
      int f = i * 2048 + tid * 8;
      int r = f >> 6, kk = f & 63;
      uint4 va = make_uint4(0u, 0u, 0u, 0u);
      if (k0 + kk < K)
        va = *reinterpret_cast<const uint4*>(A + (size_t)(row0 + r) * lda + k0 + kk);
      *reinterpret_cast<uint4*>(&As[r][kk]) = va;
    }
    // stage B: 256 cols x 64 k, fp32 global -> bf16 LDS
#pragma unroll
    for (int i = 0; i < 16; ++i) {
      int f = i * 1024 + tid * 4;
      int c = f >> 6, kk = f & 63;
      int col = colBase + c;
      float4 v = make_float4(0.f, 0.f, 0.f, 0.f);
      if (col < N && k0 + kk < K)
        v = *reinterpret_cast<const float4*>(B + (size_t)col * K + k0 + kk);
      uint2 u;
      u.x = (unsigned int)f2bf(v.x) | ((unsigned int)f2bf(v.y) << 16);
      u.y = (unsigned int)f2bf(v.z) | ((unsigned int)f2bf(v.w) << 16);
      *reinterpret_cast<uint2*>(&Bs[c][kk]) = u;
    }
    __syncthreads();
#pragma unroll
    for (int ks = 0; ks < GBK; ks += 32) {
      bf16x8 fa[4], fb[4];
#pragma unroll
      for (int mb = 0; mb < 4; ++mb)
        fa[mb] = *reinterpret_cast<const bf16x8*>(&As[mb * 16 + l15][ks + q * 8]);
#pragma unroll
      for (int nb = 0; nb < 4; ++nb)
        fb[nb] = *reinterpret_cast<const bf16x8*>(&Bs[w * 64 + nb * 16 + l15][ks + q * 8]);
#pragma unroll
      for (int mb = 0; mb < 4; ++mb)
#pragma unroll
        for (int nb = 0; nb < 4; ++nb)
          acc[mb][nb] = __builtin_amdgcn_mfma_f32_16x16x32_bf16(
              fa[mb], fb[nb], acc[mb][nb], 0, 0, 0);
    }
  }

  int colg[4];
#pragma unroll
  for (int nb = 0; nb < 4; ++nb) colg[nb] = colBase + w * 64 + nb * 16 + l15;

  if (SOFTMAX) {
    float bv[4];
#pragma unroll
    for (int nb = 0; nb < 4; ++nb) bv[nb] = (colg[nb] < N) ? bias[colg[nb]] : 0.f;
#pragma unroll
    for (int mb = 0; mb < 4; ++mb)
#pragma unroll
      for (int nb = 0; nb < 4; ++nb)
#pragma unroll
        for (int r = 0; r < 4; ++r) acc[mb][nb][r] += bv[nb];
    // raw logits -> d_out (normalized later)
#pragma unroll
    for (int mb = 0; mb < 4; ++mb)
#pragma unroll
      for (int nb = 0; nb < 4; ++nb)
        if (colg[nb] < N) {
#pragma unroll
          for (int r = 0; r < 4; ++r) {
            int rowg = row0 + mb * 16 + q * 4 + r;
            outF[(size_t)rowg * ldo + colg[nb]] = acc[mb][nb][r];
          }
        }
    // per-row (m, sumexp) over this block's 256 cols
#pragma unroll
    for (int mb = 0; mb < 4; ++mb) {
#pragma unroll
      for (int r = 0; r < 4; ++r) {
        float mx = NEG_HUGE, s = 0.f;
#pragma unroll
        for (int nb = 0; nb < 4; ++nb)
          if (colg[nb] < N) mx = fmaxf(mx, acc[mb][nb][r]);
#pragma unroll
        for (int nb = 0; nb < 4; ++nb)
          if (colg[nb] < N) s += expf(acc[mb][nb][r] - mx);
        for (int off = 1; off < 16; off <<= 1) {   // reduce over quad's 16 lanes
          float mo = __shfl_xor(mx, off);
          float so = __shfl_xor(s, off);
          mergeMS(mx, s, mo, so);
        }
        if (l15 == 0) {
          red[mb * 16 + q * 4 + r][w][0] = mx;
          red[mb * 16 + q * 4 + r][w][1] = s;
        }
      }
    }
    __syncthreads();
    if (tid < 64) {
      float m = red[tid][0][0], s = red[tid][0][1];
#pragma unroll
      for (int ww = 1; ww < 4; ++ww) mergeMS(m, s, red[tid][ww][0], red[tid][ww][1]);
      size_t pi = ((size_t)(row0 + tid) * nChunks + blockIdx.y) * 2;
      partials[pi] = m;
      partials[pi + 1] = s;
    }
  } else {
#pragma unroll
    for (int mb = 0; mb < 4; ++mb)
#pragma unroll
      for (int nb = 0; nb < 4; ++nb)
        if (colg[nb] < N) {
#pragma unroll
          for (int r = 0; r < 4; ++r) {
            int rowg = row0 + mb * 16 + q * 4 + r;
            outH[(size_t)rowg * ldh + colg[nb]] = f2bf(acc[mb][nb][r]);
          }
        }
  }
}

// ------------------------------------------------- cluster logits [512 x 3]
__global__ __launch_bounds__(192) void cluster_kernel(
    const unsigned short* __restrict__ Y0, const float* __restrict__ CW,
    const float* __restrict__ CB, float* __restrict__ CL) {
  int row = blockIdx.x;
  int w = threadIdx.x >> 6, lane = threadIdx.x & 63;
  float s = 0.f;
  for (int k = lane; k < 1024; k += 64)
    s += bf2f(Y0[row * 1024 + k]) * CW[w * 1024 + k];
  for (int off = 32; off > 0; off >>= 1) s += __shfl_xor(s, off);
  if (lane == 0) CL[row * 3 + w] = s + CB[w];
}

// ------------------------------------- reduce partials -> (m, log sumexp)
__global__ __launch_bounds__(128) void reduce_stats_kernel(
    const float* __restrict__ part, const float* __restrict__ CL,
    float* __restrict__ stats) {
  const int nch[4] = {79, 79, 625, 265};
  const long long poff[4] = {0, 80896, 161792, 801792};  // floats
  int row = blockIdx.x >> 2, b = blockIdx.x & 3;
  const float* p = part + poff[b] + (long long)row * nch[b] * 2;
  float m = NEG_HUGE, s = 0.f;
  for (int j = threadIdx.x; j < nch[b]; j += 128) mergeMS(m, s, p[j * 2], p[j * 2 + 1]);
  for (int off = 1; off < 64; off <<= 1) {
    float mo = __shfl_xor(m, off);
    float so = __shfl_xor(s, off);
    mergeMS(m, s, mo, so);
  }
  __shared__ float sm[2][2];
  int w = threadIdx.x >> 6;
  if ((threadIdx.x & 63) == 0) { sm[w][0] = m; sm[w][1] = s; }
  __syncthreads();
  if (threadIdx.x == 0) {
    mergeMS(m, s, sm[1][0], sm[1][1]);
    if (b == 0)  // head softmax includes the 3 cluster logits
      for (int c = 0; c < 3; ++c) mergeMS(m, s, CL[row * 3 + c], 1.f);
    stats[(row * 4 + b) * 2] = m;
    stats[(row * 4 + b) * 2 + 1] = logf(s);
  }
}

// ------------------------------------------------------------- normalize
// Block-per-(row, chunk): no integer division, per-row constants hoisted,
// float4 RMW with 4 independent vectors in flight per thread.
// Row base (row*267735 floats) is only 4B-aligned; lead = row & 3 scalar
// elems reach 16B alignment, then exactly 66933 float4s + (3-lead) tail.
// lead cols (<3) are bucket 0; tail cols (>=267732) are bucket 3.
__global__ __launch_bounds__(256) void normalize_kernel(
    float* __restrict__ out, const float* __restrict__ stats,
    const float* __restrict__ CL) {
  const int row = blockIdx.x;
  const float s0 = stats[row * 8 + 0] + stats[row * 8 + 1];        // m0 + L0
  const float s1 = stats[(row * 4 + 1) * 2] + stats[(row * 4 + 1) * 2 + 1]
                   - (CL[row * 3 + 0] - s0);
  const float s2 = stats[(row * 4 + 2) * 2] + stats[(row * 4 + 2) * 2 + 1]
                   - (CL[row * 3 + 1] - s0);
  const float s3 = stats[(row * 4 + 3) * 2] + stats[(row * 4 + 3) * 2 + 1]
                   - (CL[row * 3 + 2] - s0);
  float* op = out + (size_t)row * 267735LL;
  const int lead = row & 3;        // (row*267735)%4 == (row*3)%4; pad = row&3
  const int NV = 66933;            // float4 count per row (exact for any lead)
  float4* vp = reinterpret_cast<float4*>(op + lead);

  int vbase = blockIdx.y * 1024 + threadIdx.x;
#pragma unroll
  for (int i = 0; i < 4; ++i) {
    int v = vbase + i * 256;
    if (v < NV) {
      float4 x = vp[v];
      int c0 = lead + v * 4;
      x.x -= (c0     < 20000) ? s0 : (c0     < 40000) ? s1 : (c0     < 200000) ? s2 : s3;
      x.y -= (c0 + 1 < 20000) ? s0 : (c0 + 1 < 40000) ? s1 : (c0 + 1 < 200000) ? s2 : s3;
      x.z -= (c0 + 2 < 20000) ? s0 : (c0 + 2 < 40000) ? s1 : (c0 + 2 < 200000) ? s2 : s3;
      x.w -= (c0 + 3 < 20000) ? s0 : (c0 + 3 < 40000) ? s1 : (c0 + 3 < 200000) ? s2 : s3;
      vp[v] = x;
    }
  }
  if (blockIdx.y == 0 && threadIdx.x == 0) {
    for (int c = 0; c < lead; ++c) op[c] -= s0;                  // head, bucket 0
    for (int c = lead + NV * 4; c < 267735; ++c) op[c] -= s3;    // tail, bucket 3
  }
}

// ------------------------------------------------------------------ loss
__global__ __launch_bounds__(512) void loss_kernel(
    const float* __restrict__ out, const int* __restrict__ target,
    float* __restrict__ lossOut) {
  __shared__ float sm[512];
  int t = threadIdx.x;
  sm[t] = out[(size_t)t * 267735 + target[t]];  // final lp at target col
  __syncthreads();
  for (int s = 256; s > 0; s >>= 1) {
    if (t < s) sm[t] += sm[t + s];
    __syncthreads();
  }
  if (t == 0) lossOut[0] = -sm[0] / 512.f;
}

// ---------------------------------------------------------------------------
extern "C" void kernel_launch(void* const* d_in, const int* in_sizes, int n_in,
                              void* d_out, int out_size, void* d_ws, size_t ws_size,
                              hipStream_t stream) {
  const float* hidden = (const float*)d_in[0];
  const int* target = (const int*)d_in[1];
  const float* CW = (const float*)d_in[2];
  const float* CB = (const float*)d_in[3];
  const float* W[4] = {(const float*)d_in[4], (const float*)d_in[7],
                       (const float*)d_in[10], (const float*)d_in[13]};
  const float* Bb[4] = {(const float*)d_in[5], (const float*)d_in[8],
                        (const float*)d_in[11], (const float*)d_in[14]};
  const float* P[4] = {(const float*)d_in[6], (const float*)d_in[9],
                       (const float*)d_in[12], (const float*)d_in[15]};

  char* ws = (char*)d_ws;   // ~6.8 MB used
  unsigned short* hbf = (unsigned short*)(ws + 0);
  unsigned short* Y[4] = {(unsigned short*)(ws + 1048576),
                          (unsigned short*)(ws + 2097152),
                          (unsigned short*)(ws + 2359296),
                          (unsigned short*)(ws + 2424832)};
  float* CL = (float*)(ws + 2441216);
  float* stats = (float*)(ws + 2447360);
  float* part = (float*)(ws + 2463744);

  float* out = (float*)d_out;
  const int dims[4] = {1024, 256, 64, 16};
  const int nvoc[4] = {20000, 20000, 160000, 67735};
  const int colOff[4] = {0, 20000, 40000, 200000};
  const int nch[4] = {79, 79, 625, 265};
  const long long poffF[4] = {0, 80896, 161792, 801792};

  convert_h_kernel<<<512, 256, 0, stream>>>(hidden, hbf);
  for (int i = 0; i < 4; ++i) {
    dim3 g(8, (dims[i] + 255) / 256);
    gemm_bt_kernel<false><<<g, 256, 0, stream>>>(hbf, 1024, 1024, P[i], nullptr,
                                                 dims[i], nullptr, 0, Y[i], dims[i],
                                                 nullptr, 0);
  }
  cluster_kernel<<<512, 192, 0, stream>>>(Y[0], CW, CB, CL);
  for (int i = 0; i < 4; ++i) {
    dim3 g(8, nch[i]);   // x = m-tiles (fast-varying) so W tiles hit L2 across m
    gemm_bt_kernel<true><<<g, 256, 0, stream>>>(Y[i], dims[i], dims[i], W[i], Bb[i],
                                                nvoc[i], out + colOff[i], 267735LL,
                                                nullptr, 0, part + poffF[i], nch[i]);
  }
  reduce_stats_kernel<<<512 * 4, 128, 0, stream>>>(part, CL, stats);
  dim3 gn(512, 66);
  normalize_kernel<<<gn, 256, 0, stream>>>(out, stats, CL);
  loss_kernel<<<1, 512, 0, stream>>>(out, target, out + 137080320LL);
}

// Round 3
// 1374.666 us; speedup vs baseline: 1.5779x; 1.4229x over previous
//
#include <hip/hip_runtime.h>

// ---------------------------------------------------------------------------
// Adaptive softmax (TransformerXL style), MI355X/gfx950.
// R=512 rows, buckets: n={20000,20000,160000,67735}, d={1024,256,64,16}.
// Pipeline: h->bf16 | W,P->bf16 (one-time) | Y_i = h P_i^T (MFMA) | cluster
// logits | logits GEMM (MFMA, raw logits + per-block softmax partials) |
// partial reduce | normalize | loss gather.
// ---------------------------------------------------------------------------

typedef __bf16 bf16x8 __attribute__((ext_vector_type(8)));
typedef float  f32x4  __attribute__((ext_vector_type(4)));

#define NEG_HUGE (-3.402823466e38f)

__device__ __forceinline__ unsigned short f2bf(float x) {
  unsigned int u = __float_as_uint(x);
  u = (u + 0x7fffu + ((u >> 16) & 1u)) >> 16;   // RNE
  return (unsigned short)u;
}
__device__ __forceinline__ float bf2f(unsigned short h) {
  return __uint_as_float(((unsigned int)h) << 16);
}
// merge two (max, sumexp) pairs; NEG_HUGE sentinel keeps this NaN-free
__device__ __forceinline__ void mergeMS(float& m, float& s, float mo, float so) {
  float mn = fmaxf(m, mo);
  s = s * expf(m - mn) + so * expf(mo - mn);
  m = mn;
}

// ---------------------------------------------------------------- h -> bf16
__global__ __launch_bounds__(256) void convert_h_kernel(
    const float* __restrict__ h, unsigned short* __restrict__ o) {
  int i = (blockIdx.x * 256 + threadIdx.x) * 4;          // 512 blocks, exact
  float4 v = *reinterpret_cast<const float4*>(h + i);
  uint2 u;
  u.x = (unsigned int)f2bf(v.x) | ((unsigned int)f2bf(v.y) << 16);
  u.y = (unsigned int)f2bf(v.z) | ((unsigned int)f2bf(v.w) << 16);
  *reinterpret_cast<uint2*>(o + i) = u;
}

// ------------------------------------------------ W/P -> bf16 (one launch)
// 8 segments (W0..W3, P0..P3), each block owns 1024 float4s of one segment.
struct CvtDesc {
  const float* src[8];
  unsigned short* dst[8];
  int n4[8];     // float4 count per segment
  int blk0[9];   // cumulative block offsets
};

__global__ __launch_bounds__(256) void convert_w_kernel(CvtDesc d) {
  int b = blockIdx.x, seg = 0;
  while (seg < 7 && b >= d.blk0[seg + 1]) ++seg;
  const float* __restrict__ s = d.src[seg];
  unsigned short* __restrict__ o = d.dst[seg];
  const int n4 = d.n4[seg];
  int base = (b - d.blk0[seg]) * 1024 + threadIdx.x;
#pragma unroll
  for (int i = 0; i < 4; ++i) {
    int v = base + i * 256;
    if (v < n4) {
      float4 x = reinterpret_cast<const float4*>(s)[v];
      uint2 u;
      u.x = (unsigned int)f2bf(x.x) | ((unsigned int)f2bf(x.y) << 16);
      u.y = (unsigned int)f2bf(x.z) | ((unsigned int)f2bf(x.w) << 16);
      reinterpret_cast<uint2*>(o)[v] = u;
    }
  }
}

// ---------------------------------------------------------------- GEMM
// C[512, N] = A_bf16[512, K] * B[N, K]^T (+bias)
// BH=true : B is bf16 (pre-converted) -> pure uint4 staging, no VALU convert
// BH=false: B is fp32, converted to bf16 during staging (fallback path)
// SOFTMAX=true : store fp32 raw logits to outF (ld=ldo) + per-block (m,s)
// SOFTMAX=false: store bf16 to outH (ld=ldh)
constexpr int GBM = 64, GBN = 256, GBK = 64, GPK = GBK + 8;

template <bool SOFTMAX, bool BH>
__global__ __launch_bounds__(256) void gemm_bt_kernel(
    const unsigned short* __restrict__ A, int lda, int K,
    const float* __restrict__ B, const unsigned short* __restrict__ Bh,
    const float* __restrict__ bias, int N,
    float* __restrict__ outF, long long ldo,
    unsigned short* __restrict__ outH, int ldh,
    float* __restrict__ partials, int nChunks) {
  __shared__ unsigned short As[GBM][GPK];   // +8 pad keeps b128 align, spreads banks
  __shared__ unsigned short Bs[GBN][GPK];
  __shared__ float red[GBM][4][2];

  const int tid = threadIdx.x;
  const int lane = tid & 63, w = tid >> 6;
  const int q = lane >> 4, l15 = lane & 15;
  const int row0 = blockIdx.x * GBM;
  const int colBase = blockIdx.y * GBN;

  f32x4 acc[4][4];
#pragma unroll
  for (int i = 0; i < 4; ++i)
#pragma unroll
    for (int j = 0; j < 4; ++j) acc[i][j] = (f32x4){0.f, 0.f, 0.f, 0.f};

  for (int k0 = 0; k0 < K; k0 += GBK) {
    __syncthreads();
    // stage A: 64 rows x 64 k bf16 (16B per thread-iter, 2 iters)
#pragma unroll
    for (int i = 0; i < 2; ++i) {
      int f = i * 2048 + tid * 8;
      int r = f >> 6, kk = f & 63;
      uint4 va = make_uint4(0u, 0u, 0u, 0u);
      if (k0 + kk < K)
        va = *reinterpret_cast<const uint4*>(A + (size_t)(row0 + r) * lda + k0 + kk);
      *reinterpret_cast<uint4*>(&As[r][kk]) = va;
    }
    if (BH) {
      // stage B: 256 cols x 64 k bf16, straight uint4 copies (8 iters)
#pragma unroll
      for (int i = 0; i < 8; ++i) {
        int f = i * 2048 + tid * 8;
        int c = f >> 6, kk = f & 63;
        int col = colBase + c;
        uint4 v = make_uint4(0u, 0u, 0u, 0u);
        if (col < N && k0 + kk < K)
          v = *reinterpret_cast<const uint4*>(Bh + (size_t)col * K + k0 + kk);
        *reinterpret_cast<uint4*>(&Bs[c][kk]) = v;
      }
    } else {
      // stage B: 256 cols x 64 k, fp32 global -> bf16 LDS
#pragma unroll
      for (int i = 0; i < 16; ++i) {
        int f = i * 1024 + tid * 4;
        int c = f >> 6, kk = f & 63;
        int col = colBase + c;
        float4 v = make_float4(0.f, 0.f, 0.f, 0.f);
        if (col < N && k0 + kk < K)
          v = *reinterpret_cast<const float4*>(B + (size_t)col * K + k0 + kk);
        uint2 u;
        u.x = (unsigned int)f2bf(v.x) | ((unsigned int)f2bf(v.y) << 16);
        u.y = (unsigned int)f2bf(v.z) | ((unsigned int)f2bf(v.w) << 16);
        *reinterpret_cast<uint2*>(&Bs[c][kk]) = u;
      }
    }
    __syncthreads();
#pragma unroll
    for (int ks = 0; ks < GBK; ks += 32) {
      bf16x8 fa[4], fb[4];
#pragma unroll
      for (int mb = 0; mb < 4; ++mb)
        fa[mb] = *reinterpret_cast<const bf16x8*>(&As[mb * 16 + l15][ks + q * 8]);
#pragma unroll
      for (int nb = 0; nb < 4; ++nb)
        fb[nb] = *reinterpret_cast<const bf16x8*>(&Bs[w * 64 + nb * 16 + l15][ks + q * 8]);
#pragma unroll
      for (int mb = 0; mb < 4; ++mb)
#pragma unroll
        for (int nb = 0; nb < 4; ++nb)
          acc[mb][nb] = __builtin_amdgcn_mfma_f32_16x16x32_bf16(
              fa[mb], fb[nb], acc[mb][nb], 0, 0, 0);
    }
  }

  int colg[4];
#pragma unroll
  for (int nb = 0; nb < 4; ++nb) colg[nb] = colBase + w * 64 + nb * 16 + l15;

  if (SOFTMAX) {
    float bv[4];
#pragma unroll
    for (int nb = 0; nb < 4; ++nb) bv[nb] = (colg[nb] < N) ? bias[colg[nb]] : 0.f;
#pragma unroll
    for (int mb = 0; mb < 4; ++mb)
#pragma unroll
      for (int nb = 0; nb < 4; ++nb)
#pragma unroll
        for (int r = 0; r < 4; ++r) acc[mb][nb][r] += bv[nb];
    // raw logits -> d_out (normalized later)
#pragma unroll
    for (int mb = 0; mb < 4; ++mb)
#pragma unroll
      for (int nb = 0; nb < 4; ++nb)
        if (colg[nb] < N) {
#pragma unroll
          for (int r = 0; r < 4; ++r) {
            int rowg = row0 + mb * 16 + q * 4 + r;
            outF[(size_t)rowg * ldo + colg[nb]] = acc[mb][nb][r];
          }
        }
    // per-row (m, sumexp) over this block's 256 cols
#pragma unroll
    for (int mb = 0; mb < 4; ++mb) {
#pragma unroll
      for (int r = 0; r < 4; ++r) {
        float mx = NEG_HUGE, s = 0.f;
#pragma unroll
        for (int nb = 0; nb < 4; ++nb)
          if (colg[nb] < N) mx = fmaxf(mx, acc[mb][nb][r]);
#pragma unroll
        for (int nb = 0; nb < 4; ++nb)
          if (colg[nb] < N) s += expf(acc[mb][nb][r] - mx);
        for (int off = 1; off < 16; off <<= 1) {   // reduce over quad's 16 lanes
          float mo = __shfl_xor(mx, off);
          float so = __shfl_xor(s, off);
          mergeMS(mx, s, mo, so);
        }
        if (l15 == 0) {
          red[mb * 16 + q * 4 + r][w][0] = mx;
          red[mb * 16 + q * 4 + r][w][1] = s;
        }
      }
    }
    __syncthreads();
    if (tid < 64) {
      float m = red[tid][0][0], s = red[tid][0][1];
#pragma unroll
      for (int ww = 1; ww < 4; ++ww) mergeMS(m, s, red[tid][ww][0], red[tid][ww][1]);
      size_t pi = ((size_t)(row0 + tid) * nChunks + blockIdx.y) * 2;
      partials[pi] = m;
      partials[pi + 1] = s;
    }
  } else {
#pragma unroll
    for (int mb = 0; mb < 4; ++mb)
#pragma unroll
      for (int nb = 0; nb < 4; ++nb)
        if (colg[nb] < N) {
#pragma unroll
          for (int r = 0; r < 4; ++r) {
            int rowg = row0 + mb * 16 + q * 4 + r;
            outH[(size_t)rowg * ldh + colg[nb]] = f2bf(acc[mb][nb][r]);
          }
        }
  }
}

// ------------------------------------------------- cluster logits [512 x 3]
__global__ __launch_bounds__(192) void cluster_kernel(
    const unsigned short* __restrict__ Y0, const float* __restrict__ CW,
    const float* __restrict__ CB, float* __restrict__ CL) {
  int row = blockIdx.x;
  int w = threadIdx.x >> 6, lane = threadIdx.x & 63;
  float s = 0.f;
  for (int k = lane; k < 1024; k += 64)
    s += bf2f(Y0[row * 1024 + k]) * CW[w * 1024 + k];
  for (int off = 32; off > 0; off >>= 1) s += __shfl_xor(s, off);
  if (lane == 0) CL[row * 3 + w] = s + CB[w];
}

// ------------------------------------- reduce partials -> (m, log sumexp)
__global__ __launch_bounds__(128) void reduce_stats_kernel(
    const float* __restrict__ part, const float* __restrict__ CL,
    float* __restrict__ stats) {
  const int nch[4] = {79, 79, 625, 265};
  const long long poff[4] = {0, 80896, 161792, 801792};  // floats
  int row = blockIdx.x >> 2, b = blockIdx.x & 3;
  const float* p = part + poff[b] + (long long)row * nch[b] * 2;
  float m = NEG_HUGE, s = 0.f;
  for (int j = threadIdx.x; j < nch[b]; j += 128) mergeMS(m, s, p[j * 2], p[j * 2 + 1]);
  for (int off = 1; off < 64; off <<= 1) {
    float mo = __shfl_xor(m, off);
    float so = __shfl_xor(s, off);
    mergeMS(m, s, mo, so);
  }
  __shared__ float sm[2][2];
  int w = threadIdx.x >> 6;
  if ((threadIdx.x & 63) == 0) { sm[w][0] = m; sm[w][1] = s; }
  __syncthreads();
  if (threadIdx.x == 0) {
    mergeMS(m, s, sm[1][0], sm[1][1]);
    if (b == 0)  // head softmax includes the 3 cluster logits
      for (int c = 0; c < 3; ++c) mergeMS(m, s, CL[row * 3 + c], 1.f);
    stats[(row * 4 + b) * 2] = m;
    stats[(row * 4 + b) * 2 + 1] = logf(s);
  }
}

// ------------------------------------------------------------- normalize
// Block-per-(row, chunk): no integer division, per-row constants hoisted,
// float4 RMW with 4 independent vectors in flight per thread.
__global__ __launch_bounds__(256) void normalize_kernel(
    float* __restrict__ out, const float* __restrict__ stats,
    const float* __restrict__ CL) {
  const int row = blockIdx.x;
  const float s0 = stats[row * 8 + 0] + stats[row * 8 + 1];        // m0 + L0
  const float s1 = stats[(row * 4 + 1) * 2] + stats[(row * 4 + 1) * 2 + 1]
                   - (CL[row * 3 + 0] - s0);
  const float s2 = stats[(row * 4 + 2) * 2] + stats[(row * 4 + 2) * 2 + 1]
                   - (CL[row * 3 + 1] - s0);
  const float s3 = stats[(row * 4 + 3) * 2] + stats[(row * 4 + 3) * 2 + 1]
                   - (CL[row * 3 + 2] - s0);
  float* op = out + (size_t)row * 267735LL;
  const int lead = row & 3;        // (row*267735)%4 == (row*3)%4
  const int NV = 66933;            // float4 count per row (exact for any lead)
  float4* vp = reinterpret_cast<float4*>(op + lead);

  int vbase = blockIdx.y * 1024 + threadIdx.x;
#pragma unroll
  for (int i = 0; i < 4; ++i) {
    int v = vbase + i * 256;
    if (v < NV) {
      float4 x = vp[v];
      int c0 = lead + v * 4;
      x.x -= (c0     < 20000) ? s0 : (c0     < 40000) ? s1 : (c0     < 200000) ? s2 : s3;
      x.y -= (c0 + 1 < 20000) ? s0 : (c0 + 1 < 40000) ? s1 : (c0 + 1 < 200000) ? s2 : s3;
      x.z -= (c0 + 2 < 20000) ? s0 : (c0 + 2 < 40000) ? s1 : (c0 + 2 < 200000) ? s2 : s3;
      x.w -= (c0 + 3 < 20000) ? s0 : (c0 + 3 < 40000) ? s1 : (c0 + 3 < 200000) ? s2 : s3;
      vp[v] = x;
    }
  }
  if (blockIdx.y == 0 && threadIdx.x == 0) {
    for (int c = 0; c < lead; ++c) op[c] -= s0;                  // head, bucket 0
    for (int c = lead + NV * 4; c < 267735; ++c) op[c] -= s3;    // tail, bucket 3
  }
}

// ------------------------------------------------------------------ loss
__global__ __launch_bounds__(512) void loss_kernel(
    const float* __restrict__ out, const int* __restrict__ target,
    float* __restrict__ lossOut) {
  __shared__ float sm[512];
  int t = threadIdx.x;
  sm[t] = out[(size_t)t * 267735 + target[t]];  // final lp at target col
  __syncthreads();
  for (int s = 256; s > 0; s >>= 1) {
    if (t < s) sm[t] += sm[t + s];
    __syncthreads();
  }
  if (t == 0) lossOut[0] = -sm[0] / 512.f;
}

// ---------------------------------------------------------------------------
extern "C" void kernel_launch(void* const* d_in, const int* in_sizes, int n_in,
                              void* d_out, int out_size, void* d_ws, size_t ws_size,
                              hipStream_t stream) {
  const float* hidden = (const float*)d_in[0];
  const int* target = (const int*)d_in[1];
  const float* CW = (const float*)d_in[2];
  const float* CB = (const float*)d_in[3];
  const float* W[4] = {(const float*)d_in[4], (const float*)d_in[7],
                       (const float*)d_in[10], (const float*)d_in[13]};
  const float* Bb[4] = {(const float*)d_in[5], (const float*)d_in[8],
                        (const float*)d_in[11], (const float*)d_in[14]};
  const float* P[4] = {(const float*)d_in[6], (const float*)d_in[9],
                       (const float*)d_in[12], (const float*)d_in[15]};

  char* ws = (char*)d_ws;
  unsigned short* hbf = (unsigned short*)(ws + 0);
  unsigned short* Y[4] = {(unsigned short*)(ws + 1048576),
                          (unsigned short*)(ws + 2097152),
                          (unsigned short*)(ws + 2359296),
                          (unsigned short*)(ws + 2424832)};
  float* CL = (float*)(ws + 2441216);
  float* stats = (float*)(ws + 2447360);
  float* part = (float*)(ws + 2463744);   // 4,292,608 B -> ends 6,756,352

  // bf16 weight region (needs ws_size >= 83,393,248)
  const unsigned long long WBF = 6760448ull;
  unsigned short* Wb[4] = {(unsigned short*)(ws + WBF),
                           (unsigned short*)(ws + WBF + 40960000ull),
                           (unsigned short*)(ws + WBF + 51200000ull),
                           (unsigned short*)(ws + WBF + 71680000ull)};
  unsigned short* Pb[4] = {(unsigned short*)(ws + WBF + 73847520ull),
                           (unsigned short*)(ws + WBF + 75944672ull),
                           (unsigned short*)(ws + WBF + 76468960ull),
                           (unsigned short*)(ws + WBF + 76600032ull)};
  const bool BH = (ws_size >= WBF + 76632800ull);

  float* out = (float*)d_out;
  const int dims[4] = {1024, 256, 64, 16};
  const int nvoc[4] = {20000, 20000, 160000, 67735};
  const int colOff[4] = {0, 20000, 40000, 200000};
  const int nch[4] = {79, 79, 625, 265};
  const long long poffF[4] = {0, 80896, 161792, 801792};

  convert_h_kernel<<<512, 256, 0, stream>>>(hidden, hbf);

  if (BH) {
    CvtDesc d;
    const float* srcs[8] = {W[0], W[1], W[2], W[3], P[0], P[1], P[2], P[3]};
    unsigned short* dsts[8] = {Wb[0], Wb[1], Wb[2], Wb[3], Pb[0], Pb[1], Pb[2], Pb[3]};
    const int n4s[8] = {5120000, 1280000, 2560000, 270940, 262144, 65536, 16384, 4096};
    const int blk0s[9] = {0, 5000, 6250, 8750, 9015, 9271, 9335, 9351, 9355};
    for (int i = 0; i < 8; ++i) { d.src[i] = srcs[i]; d.dst[i] = dsts[i]; d.n4[i] = n4s[i]; }
    for (int i = 0; i < 9; ++i) d.blk0[i] = blk0s[i];
    convert_w_kernel<<<9355, 256, 0, stream>>>(d);
  }

  for (int i = 0; i < 4; ++i) {
    dim3 g(8, (dims[i] + 255) / 256);
    if (BH)
      gemm_bt_kernel<false, true><<<g, 256, 0, stream>>>(
          hbf, 1024, 1024, nullptr, Pb[i], nullptr, dims[i],
          nullptr, 0, Y[i], dims[i], nullptr, 0);
    else
      gemm_bt_kernel<false, false><<<g, 256, 0, stream>>>(
          hbf, 1024, 1024, P[i], nullptr, nullptr, dims[i],
          nullptr, 0, Y[i], dims[i], nullptr, 0);
  }
  cluster_kernel<<<512, 192, 0, stream>>>(Y[0], CW, CB, CL);
  for (int i = 0; i < 4; ++i) {
    dim3 g(8, nch[i]);   // x = m-tiles (fast-varying) so W tiles hit L2 across m
    if (BH)
      gemm_bt_kernel<true, true><<<g, 256, 0, stream>>>(
          Y[i], dims[i], dims[i], nullptr, Wb[i], Bb[i], nvoc[i],
          out + colOff[i], 267735LL, nullptr, 0, part + poffF[i], nch[i]);
    else
      gemm_bt_kernel<true, false><<<g, 256, 0, stream>>>(
          Y[i], dims[i], dims[i], W[i], nullptr, Bb[i], nvoc[i],
          out + colOff[i], 267735LL, nullptr, 0, part + poffF[i], nch[i]);
  }
  reduce_stats_kernel<<<512 * 4, 128, 0, stream>>>(part, CL, stats);
  dim3 gn(512, 66);
  normalize_kernel<<<gn, 256, 0, stream>>>(out, stats, CL);
  loss_kernel<<<1, 512, 0, stream>>>(out, target, out + 137080320LL);
}

// Round 5
// 1318.208 us; speedup vs baseline: 1.6455x; 1.0428x over previous
//
#include <hip/hip_runtime.h>

// ---------------------------------------------------------------------------
// Adaptive softmax (TransformerXL style), MI355X/gfx950.
// R=512 rows, buckets: n={20000,20000,160000,67735}, d={1024,256,64,16}.
// Pipeline: h->bf16 | W,P->bf16 (one-time, W3 zero-padded K16->32) |
// Y_i = h P_i^T (reg MFMA) | cluster logits | logits GEMM (reg MFMA, no LDS,
// raw logits + per-block softmax partials; K<=64 buckets keep B in registers
// and loop all m-tiles) | partial reduce | normalize | loss gather.
// ---------------------------------------------------------------------------

typedef __bf16 bf16x8 __attribute__((ext_vector_type(8)));
typedef float  f32x4  __attribute__((ext_vector_type(4)));

#define NEG_HUGE (-3.402823466e38f)

__device__ __forceinline__ unsigned short f2bf(float x) {
  unsigned int u = __float_as_uint(x);
  u = (u + 0x7fffu + ((u >> 16) & 1u)) >> 16;   // RNE
  return (unsigned short)u;
}
__device__ __forceinline__ float bf2f(unsigned short h) {
  return __uint_as_float(((unsigned int)h) << 16);
}
// merge two (max, sumexp) pairs; NEG_HUGE sentinel keeps this NaN-free
__device__ __forceinline__ void mergeMS(float& m, float& s, float mo, float so) {
  float mn = fmaxf(m, mo);
  s = s * __expf(m - mn) + so * __expf(mo - mn);
  m = mn;
}

// ---------------------------------------------------------------- h -> bf16
__global__ __launch_bounds__(256) void convert_h_kernel(
    const float* __restrict__ h, unsigned short* __restrict__ o) {
  int i = (blockIdx.x * 256 + threadIdx.x) * 4;          // 512 blocks, exact
  float4 v = *reinterpret_cast<const float4*>(h + i);
  uint2 u;
  u.x = (unsigned int)f2bf(v.x) | ((unsigned int)f2bf(v.y) << 16);
  u.y = (unsigned int)f2bf(v.z) | ((unsigned int)f2bf(v.w) << 16);
  *reinterpret_cast<uint2*>(o + i) = u;
}

// ------------------------------------------------ W/P -> bf16 (one launch)
// 7 segments (W0..W2, P0..P3); W3 handled by convert_w3_kernel (padded).
struct CvtDesc {
  const float* src[7];
  unsigned short* dst[7];
  int n4[7];     // float4 count per segment
  int blk0[8];   // cumulative block offsets
};

__global__ __launch_bounds__(256) void convert_w_kernel(CvtDesc d) {
  int b = blockIdx.x, seg = 0;
  while (seg < 6 && b >= d.blk0[seg + 1]) ++seg;
  const float* __restrict__ s = d.src[seg];
  unsigned short* __restrict__ o = d.dst[seg];
  const int n4 = d.n4[seg];
  int base = (b - d.blk0[seg]) * 1024 + threadIdx.x;
#pragma unroll
  for (int i = 0; i < 4; ++i) {
    int v = base + i * 256;
    if (v < n4) {
      float4 x = reinterpret_cast<const float4*>(s)[v];
      uint2 u;
      u.x = (unsigned int)f2bf(x.x) | ((unsigned int)f2bf(x.y) << 16);
      u.y = (unsigned int)f2bf(x.z) | ((unsigned int)f2bf(x.w) << 16);
      reinterpret_cast<uint2*>(o)[v] = u;
    }
  }
}

// W3 [67735,16] fp32 -> bf16 padded to [67735,32] (cols 16..31 zero).
// 4 threads per row: j<2 convert 8 floats -> uint4; j>=2 write zero uint4.
__global__ __launch_bounds__(256) void convert_w3_kernel(
    const float* __restrict__ s, unsigned short* __restrict__ o) {
  int t = blockIdx.x * 256 + threadIdx.x;
  int row = t >> 2, j = t & 3;
  if (row >= 67735) return;
  uint4 u = make_uint4(0u, 0u, 0u, 0u);
  if (j < 2) {
    float4 a = reinterpret_cast<const float4*>(s)[row * 4 + j * 2];
    float4 b = reinterpret_cast<const float4*>(s)[row * 4 + j * 2 + 1];
    u.x = (unsigned int)f2bf(a.x) | ((unsigned int)f2bf(a.y) << 16);
    u.y = (unsigned int)f2bf(a.z) | ((unsigned int)f2bf(a.w) << 16);
    u.z = (unsigned int)f2bf(b.x) | ((unsigned int)f2bf(b.y) << 16);
    u.w = (unsigned int)f2bf(b.z) | ((unsigned int)f2bf(b.w) << 16);
  }
  reinterpret_cast<uint4*>(o)[row * 4 + j] = u;
}

// -------------------------------------------- register GEMM (no LDS, bf16 B)
// C[512, N] = A_bf16[512, K] * B_bf16[N, K]^T (+bias). 64x256 per block,
// 4 waves; each wave owns 64 distinct cols -> B needs no sharing; A is
// L1/L2-resident. No barriers in the K-loop.
template <bool SOFTMAX>
__global__ __launch_bounds__(256) void gemm_reg_kernel(
    const unsigned short* __restrict__ A, int lda, int K,
    const unsigned short* __restrict__ Bh, int ldb,
    const float* __restrict__ bias, int N,
    float* __restrict__ outF, long long ldo,
    unsigned short* __restrict__ outH, int ldh,
    float* __restrict__ partials, int nChunks) {
  __shared__ float red[64][4][2];
  const int tid = threadIdx.x;
  const int lane = tid & 63, w = tid >> 6;
  const int q = lane >> 4, l15 = lane & 15;
  const int row0 = blockIdx.x * 64;
  const int colBase = blockIdx.y * 256;

  const char* Ac = (const char*)A;
  const char* Bc = (const char*)Bh;
  int colg[4];
  unsigned aoff[4], boff[4];
#pragma unroll
  for (int nb = 0; nb < 4; ++nb) {
    colg[nb] = colBase + w * 64 + nb * 16 + l15;
    int cl = colg[nb] < N ? colg[nb] : N - 1;
    boff[nb] = (unsigned)((cl * ldb + q * 8) * 2);
  }
#pragma unroll
  for (int mb = 0; mb < 4; ++mb)
    aoff[mb] = (unsigned)(((row0 + mb * 16 + l15) * lda + q * 8) * 2);

  f32x4 acc[4][4];
#pragma unroll
  for (int i = 0; i < 4; ++i)
#pragma unroll
    for (int j = 0; j < 4; ++j) acc[i][j] = (f32x4){0.f, 0.f, 0.f, 0.f};

  for (int k = 0; k < K; k += 32) {
    bf16x8 fa[4], fb[4];
#pragma unroll
    for (int mb = 0; mb < 4; ++mb)
      fa[mb] = *reinterpret_cast<const bf16x8*>(Ac + aoff[mb] + 2 * k);
#pragma unroll
    for (int nb = 0; nb < 4; ++nb)
      fb[nb] = *reinterpret_cast<const bf16x8*>(Bc + boff[nb] + 2 * k);
#pragma unroll
    for (int mb = 0; mb < 4; ++mb)
#pragma unroll
      for (int nb = 0; nb < 4; ++nb)
        acc[mb][nb] = __builtin_amdgcn_mfma_f32_16x16x32_bf16(
            fa[mb], fb[nb], acc[mb][nb], 0, 0, 0);
  }

  if (SOFTMAX) {
    float bv[4];
#pragma unroll
    for (int nb = 0; nb < 4; ++nb) bv[nb] = (colg[nb] < N) ? bias[colg[nb]] : 0.f;
#pragma unroll
    for (int mb = 0; mb < 4; ++mb)
#pragma unroll
      for (int nb = 0; nb < 4; ++nb)
#pragma unroll
        for (int r = 0; r < 4; ++r) acc[mb][nb][r] += bv[nb];
#pragma unroll
    for (int mb = 0; mb < 4; ++mb)
#pragma unroll
      for (int nb = 0; nb < 4; ++nb)
        if (colg[nb] < N) {
#pragma unroll
          for (int r = 0; r < 4; ++r) {
            int rowg = row0 + mb * 16 + q * 4 + r;
            outF[(size_t)rowg * ldo + colg[nb]] = acc[mb][nb][r];
          }
        }
#pragma unroll
    for (int mb = 0; mb < 4; ++mb) {
#pragma unroll
      for (int r = 0; r < 4; ++r) {
        float mx = NEG_HUGE, s = 0.f;
#pragma unroll
        for (int nb = 0; nb < 4; ++nb)
          if (colg[nb] < N) mx = fmaxf(mx, acc[mb][nb][r]);
#pragma unroll
        for (int nb = 0; nb < 4; ++nb)
          if (colg[nb] < N) s += __expf(acc[mb][nb][r] - mx);
        for (int off = 1; off < 16; off <<= 1) {   // reduce over quad's 16 lanes
          float mo = __shfl_xor(mx, off);
          float so = __shfl_xor(s, off);
          mergeMS(mx, s, mo, so);
        }
        if (l15 == 0) {
          red[mb * 16 + q * 4 + r][w][0] = mx;
          red[mb * 16 + q * 4 + r][w][1] = s;
        }
      }
    }
    __syncthreads();
    if (tid < 64) {
      float m = red[tid][0][0], s = red[tid][0][1];
#pragma unroll
      for (int ww = 1; ww < 4; ++ww) mergeMS(m, s, red[tid][ww][0], red[tid][ww][1]);
      size_t pi = ((size_t)(row0 + tid) * nChunks + blockIdx.y) * 2;
      partials[pi] = m;
      partials[pi + 1] = s;
    }
  } else {
    // ldh may exceed N (padded store width); pad cols get zeros
#pragma unroll
    for (int mb = 0; mb < 4; ++mb)
#pragma unroll
      for (int nb = 0; nb < 4; ++nb)
        if (colg[nb] < ldh) {
#pragma unroll
          for (int r = 0; r < 4; ++r) {
            int rowg = row0 + mb * 16 + q * 4 + r;
            outH[(size_t)rowg * ldh + colg[nb]] =
                (colg[nb] < N) ? f2bf(acc[mb][nb][r]) : (unsigned short)0;
          }
        }
  }
}

// ------------------- register GEMM, B-in-registers, m-loop (K = KS*32 <= 64)
// One block per 256-col chunk; B fragments loaded ONCE, then all 8 m-tiles
// computed -> B fetched 1x total (was 8x). Logits+softmax partials only.
template <int KS>
__global__ __launch_bounds__(256) void gemm_reg_mloop_kernel(
    const unsigned short* __restrict__ A, int lda,
    const unsigned short* __restrict__ Bh, int ldb,
    const float* __restrict__ bias, int N,
    float* __restrict__ outF, long long ldo,
    float* __restrict__ partials, int nChunks) {
  __shared__ float red[64][4][2];
  const int tid = threadIdx.x;
  const int lane = tid & 63, w = tid >> 6;
  const int q = lane >> 4, l15 = lane & 15;
  const int colBase = blockIdx.x * 256;

  const char* Ac = (const char*)A;
  const char* Bc = (const char*)Bh;
  int colg[4];
  float bv[4];
  bf16x8 fbr[KS][4];
#pragma unroll
  for (int nb = 0; nb < 4; ++nb) {
    colg[nb] = colBase + w * 64 + nb * 16 + l15;
    int cl = colg[nb] < N ? colg[nb] : N - 1;
    bv[nb] = (colg[nb] < N) ? bias[colg[nb]] : 0.f;
#pragma unroll
    for (int s = 0; s < KS; ++s)
      fbr[s][nb] = *reinterpret_cast<const bf16x8*>(
          Bc + (size_t)((cl * ldb + s * 32 + q * 8) * 2));
  }

  for (int m = 0; m < 8; ++m) {
    const int row0 = m * 64;
    f32x4 acc[4][4];
#pragma unroll
    for (int i = 0; i < 4; ++i)
#pragma unroll
      for (int j = 0; j < 4; ++j) acc[i][j] = (f32x4){0.f, 0.f, 0.f, 0.f};
#pragma unroll
    for (int s = 0; s < KS; ++s) {
      bf16x8 fa[4];
#pragma unroll
      for (int mb = 0; mb < 4; ++mb)
        fa[mb] = *reinterpret_cast<const bf16x8*>(
            Ac + (size_t)(((row0 + mb * 16 + l15) * lda + s * 32 + q * 8) * 2));
#pragma unroll
      for (int mb = 0; mb < 4; ++mb)
#pragma unroll
        for (int nb = 0; nb < 4; ++nb)
          acc[mb][nb] = __builtin_amdgcn_mfma_f32_16x16x32_bf16(
              fa[mb], fbr[s][nb], acc[mb][nb], 0, 0, 0);
    }
#pragma unroll
    for (int mb = 0; mb < 4; ++mb)
#pragma unroll
      for (int nb = 0; nb < 4; ++nb)
#pragma unroll
        for (int r = 0; r < 4; ++r) acc[mb][nb][r] += bv[nb];
#pragma unroll
    for (int mb = 0; mb < 4; ++mb)
#pragma unroll
      for (int nb = 0; nb < 4; ++nb)
        if (colg[nb] < N) {
#pragma unroll
          for (int r = 0; r < 4; ++r) {
            int rowg = row0 + mb * 16 + q * 4 + r;
            outF[(size_t)rowg * ldo + colg[nb]] = acc[mb][nb][r];
          }
        }
#pragma unroll
    for (int mb = 0; mb < 4; ++mb) {
#pragma unroll
      for (int r = 0; r < 4; ++r) {
        float mx = NEG_HUGE, s = 0.f;
#pragma unroll
        for (int nb = 0; nb < 4; ++nb)
          if (colg[nb] < N) mx = fmaxf(mx, acc[mb][nb][r]);
#pragma unroll
        for (int nb = 0; nb < 4; ++nb)
          if (colg[nb] < N) s += __expf(acc[mb][nb][r] - mx);
        for (int off = 1; off < 16; off <<= 1) {
          float mo = __shfl_xor(mx, off);
          float so = __shfl_xor(s, off);
          mergeMS(mx, s, mo, so);
        }
        if (l15 == 0) {
          red[mb * 16 + q * 4 + r][w][0] = mx;
          red[mb * 16 + q * 4 + r][w][1] = s;
        }
      }
    }
    __syncthreads();
    if (tid < 64) {
      float mm = red[tid][0][0], s = red[tid][0][1];
#pragma unroll
      for (int ww = 1; ww < 4; ++ww) mergeMS(mm, s, red[tid][ww][0], red[tid][ww][1]);
      size_t pi = ((size_t)(row0 + tid) * nChunks + blockIdx.x) * 2;
      partials[pi] = mm;
      partials[pi + 1] = s;
    }
    __syncthreads();   // red reused next m-iter
  }
}

// ------------------------------------------------ fallback GEMM (fp32 B, LDS)
constexpr int GBM = 64, GBN = 256, GBK = 64, GPK = GBK + 8;

template <bool SOFTMAX>
__global__ __launch_bounds__(256) void gemm_bt_kernel(
    const unsigned short* __restrict__ A, int lda, int K,
    const float* __restrict__ B, const float* __restrict__ bias, int N,
    float* __restrict__ outF, long long ldo,
    unsigned short* __restrict__ outH, int ldh,
    float* __restrict__ partials, int nChunks) {
  __shared__ unsigned short As[GBM][GPK];
  __shared__ unsigned short Bs[GBN][GPK];
  __shared__ float red[GBM][4][2];

  const int tid = threadIdx.x;
  const int lane = tid & 63, w = tid >> 6;
  const int q = lane >> 4, l15 = lane & 15;
  const int row0 = blockIdx.x * GBM;
  const int colBase = blockIdx.y * GBN;

  f32x4 acc[4][4];
#pragma unroll
  for (int i = 0; i < 4; ++i)
#pragma unroll
    for (int j = 0; j < 4; ++j) acc[i][j] = (f32x4){0.f, 0.f, 0.f, 0.f};

  for (int k0 = 0; k0 < K; k0 += GBK) {
    __syncthreads();
#pragma unroll
    for (int i = 0; i < 2; ++i) {
      int f = i * 2048 + tid * 8;
      int r = f >> 6, kk = f & 63;
      uint4 va = make_uint4(0u, 0u, 0u, 0u);
      if (k0 + kk < K)
        va = *reinterpret_cast<const uint4*>(A + (size_t)(row0 + r) * lda + k0 + kk);
      *reinterpret_cast<uint4*>(&As[r][kk]) = va;
    }
#pragma unroll
    for (int i = 0; i < 16; ++i) {
      int f = i * 1024 + tid * 4;
      int c = f >> 6, kk = f & 63;
      int col = colBase + c;
      float4 v = make_float4(0.f, 0.f, 0.f, 0.f);
      if (col < N && k0 + kk < K)
        v = *reinterpret_cast<const float4*>(B + (size_t)col * K + k0 + kk);
      uint2 u;
      u.x = (unsigned int)f2bf(v.x) | ((unsigned int)f2bf(v.y) << 16);
      u.y = (unsigned int)f2bf(v.z) | ((unsigned int)f2bf(v.w) << 16);
      *reinterpret_cast<uint2*>(&Bs[c][kk]) = u;
    }
    __syncthreads();
#pragma unroll
    for (int ks = 0; ks < GBK; ks += 32) {
      bf16x8 fa[4], fb[4];
#pragma unroll
      for (int mb = 0; mb < 4; ++mb)
        fa[mb] = *reinterpret_cast<const bf16x8*>(&As[mb * 16 + l15][ks + q * 8]);
#pragma unroll
      for (int nb = 0; nb < 4; ++nb)
        fb[nb] = *reinterpret_cast<const bf16x8*>(&Bs[w * 64 + nb * 16 + l15][ks + q * 8]);
#pragma unroll
      for (int mb = 0; mb < 4; ++mb)
#pragma unroll
        for (int nb = 0; nb < 4; ++nb)
          acc[mb][nb] = __builtin_amdgcn_mfma_f32_16x16x32_bf16(
              fa[mb], fb[nb], acc[mb][nb], 0, 0, 0);
    }
  }

  int colg[4];
#pragma unroll
  for (int nb = 0; nb < 4; ++nb) colg[nb] = colBase + w * 64 + nb * 16 + l15;

  if (SOFTMAX) {
    float bv[4];
#pragma unroll
    for (int nb = 0; nb < 4; ++nb) bv[nb] = (colg[nb] < N) ? bias[colg[nb]] : 0.f;
#pragma unroll
    for (int mb = 0; mb < 4; ++mb)
#pragma unroll
      for (int nb = 0; nb < 4; ++nb)
#pragma unroll
        for (int r = 0; r < 4; ++r) acc[mb][nb][r] += bv[nb];
#pragma unroll
    for (int mb = 0; mb < 4; ++mb)
#pragma unroll
      for (int nb = 0; nb < 4; ++nb)
        if (colg[nb] < N) {
#pragma unroll
          for (int r = 0; r < 4; ++r) {
            int rowg = row0 + mb * 16 + q * 4 + r;
            outF[(size_t)rowg * ldo + colg[nb]] = acc[mb][nb][r];
          }
        }
#pragma unroll
    for (int mb = 0; mb < 4; ++mb) {
#pragma unroll
      for (int r = 0; r < 4; ++r) {
        float mx = NEG_HUGE, s = 0.f;
#pragma unroll
        for (int nb = 0; nb < 4; ++nb)
          if (colg[nb] < N) mx = fmaxf(mx, acc[mb][nb][r]);
#pragma unroll
        for (int nb = 0; nb < 4; ++nb)
          if (colg[nb] < N) s += __expf(acc[mb][nb][r] - mx);
        for (int off = 1; off < 16; off <<= 1) {
          float mo = __shfl_xor(mx, off);
          float so = __shfl_xor(s, off);
          mergeMS(mx, s, mo, so);
        }
        if (l15 == 0) {
          red[mb * 16 + q * 4 + r][w][0] = mx;
          red[mb * 16 + q * 4 + r][w][1] = s;
        }
      }
    }
    __syncthreads();
    if (tid < 64) {
      float m = red[tid][0][0], s = red[tid][0][1];
#pragma unroll
      for (int ww = 1; ww < 4; ++ww) mergeMS(m, s, red[tid][ww][0], red[tid][ww][1]);
      size_t pi = ((size_t)(row0 + tid) * nChunks + blockIdx.y) * 2;
      partials[pi] = m;
      partials[pi + 1] = s;
    }
  } else {
#pragma unroll
    for (int mb = 0; mb < 4; ++mb)
#pragma unroll
      for (int nb = 0; nb < 4; ++nb)
        if (colg[nb] < N) {
#pragma unroll
          for (int r = 0; r < 4; ++r) {
            int rowg = row0 + mb * 16 + q * 4 + r;
            outH[(size_t)rowg * ldh + colg[nb]] = f2bf(acc[mb][nb][r]);
          }
        }
  }
}

// ------------------------------------------------- cluster logits [512 x 3]
__global__ __launch_bounds__(192) void cluster_kernel(
    const unsigned short* __restrict__ Y0, const float* __restrict__ CW,
    const float* __restrict__ CB, float* __restrict__ CL) {
  int row = blockIdx.x;
  int w = threadIdx.x >> 6, lane = threadIdx.x & 63;
  float s = 0.f;
  for (int k = lane; k < 1024; k += 64)
    s += bf2f(Y0[row * 1024 + k]) * CW[w * 1024 + k];
  for (int off = 32; off > 0; off >>= 1) s += __shfl_xor(s, off);
  if (lane == 0) CL[row * 3 + w] = s + CB[w];
}

// ------------------------------------- reduce partials -> (m, log sumexp)
__global__ __launch_bounds__(128) void reduce_stats_kernel(
    const float* __restrict__ part, const float* __restrict__ CL,
    float* __restrict__ stats) {
  const int nch[4] = {79, 79, 625, 265};
  const long long poff[4] = {0, 80896, 161792, 801792};  // floats
  int row = blockIdx.x >> 2, b = blockIdx.x & 3;
  const float* p = part + poff[b] + (long long)row * nch[b] * 2;
  float m = NEG_HUGE, s = 0.f;
  for (int j = threadIdx.x; j < nch[b]; j += 128) mergeMS(m, s, p[j * 2], p[j * 2 + 1]);
  for (int off = 1; off < 64; off <<= 1) {
    float mo = __shfl_xor(m, off);
    float so = __shfl_xor(s, off);
    mergeMS(m, s, mo, so);
  }
  __shared__ float sm[2][2];
  int w = threadIdx.x >> 6;
  if ((threadIdx.x & 63) == 0) { sm[w][0] = m; sm[w][1] = s; }
  __syncthreads();
  if (threadIdx.x == 0) {
    mergeMS(m, s, sm[1][0], sm[1][1]);
    if (b == 0)  // head softmax includes the 3 cluster logits
      for (int c = 0; c < 3; ++c) mergeMS(m, s, CL[row * 3 + c], 1.f);
    stats[(row * 4 + b) * 2] = m;
    stats[(row * 4 + b) * 2 + 1] = logf(s);
  }
}

// ------------------------------------------------------------- normalize
__global__ __launch_bounds__(256) void normalize_kernel(
    float* __restrict__ out, const float* __restrict__ stats,
    const float* __restrict__ CL) {
  const int row = blockIdx.x;
  const float s0 = stats[row * 8 + 0] + stats[row * 8 + 1];        // m0 + L0
  const float s1 = stats[(row * 4 + 1) * 2] + stats[(row * 4 + 1) * 2 + 1]
                   - (CL[row * 3 + 0] - s0);
  const float s2 = stats[(row * 4 + 2) * 2] + stats[(row * 4 + 2) * 2 + 1]
                   - (CL[row * 3 + 1] - s0);
  const float s3 = stats[(row * 4 + 3) * 2] + stats[(row * 4 + 3) * 2 + 1]
                   - (CL[row * 3 + 2] - s0);
  float* op = out + (size_t)row * 267735LL;
  const int lead = row & 3;        // (row*267735)%4 == (row*3)%4
  const int NV = 66933;            // float4 count per row (exact for any lead)
  float4* vp = reinterpret_cast<float4*>(op + lead);

  int vbase = blockIdx.y * 1024 + threadIdx.x;
#pragma unroll
  for (int i = 0; i < 4; ++i) {
    int v = vbase + i * 256;
    if (v < NV) {
      float4 x = vp[v];
      int c0 = lead + v * 4;
      x.x -= (c0     < 20000) ? s0 : (c0     < 40000) ? s1 : (c0     < 200000) ? s2 : s3;
      x.y -= (c0 + 1 < 20000) ? s0 : (c0 + 1 < 40000) ? s1 : (c0 + 1 < 200000) ? s2 : s3;
      x.z -= (c0 + 2 < 20000) ? s0 : (c0 + 2 < 40000) ? s1 : (c0 + 2 < 200000) ? s2 : s3;
      x.w -= (c0 + 3 < 20000) ? s0 : (c0 + 3 < 40000) ? s1 : (c0 + 3 < 200000) ? s2 : s3;
      vp[v] = x;
    }
  }
  if (blockIdx.y == 0 && threadIdx.x == 0) {
    for (int c = 0; c < lead; ++c) op[c] -= s0;                  // head, bucket 0
    for (int c = lead + NV * 4; c < 267735; ++c) op[c] -= s3;    // tail, bucket 3
  }
}

// ------------------------------------------------------------------ loss
__global__ __launch_bounds__(512) void loss_kernel(
    const float* __restrict__ out, const int* __restrict__ target,
    float* __restrict__ lossOut) {
  __shared__ float sm[512];
  int t = threadIdx.x;
  sm[t] = out[(size_t)t * 267735 + target[t]];  // final lp at target col
  __syncthreads();
  for (int s = 256; s > 0; s >>= 1) {
    if (t < s) sm[t] += sm[t + s];
    __syncthreads();
  }
  if (t == 0) lossOut[0] = -sm[0] / 512.f;
}

// ---------------------------------------------------------------------------
extern "C" void kernel_launch(void* const* d_in, const int* in_sizes, int n_in,
                              void* d_out, int out_size, void* d_ws, size_t ws_size,
                              hipStream_t stream) {
  const float* hidden = (const float*)d_in[0];
  const int* target = (const int*)d_in[1];
  const float* CW = (const float*)d_in[2];
  const float* CB = (const float*)d_in[3];
  const float* W[4] = {(const float*)d_in[4], (const float*)d_in[7],
                       (const float*)d_in[10], (const float*)d_in[13]};
  const float* Bb[4] = {(const float*)d_in[5], (const float*)d_in[8],
                        (const float*)d_in[11], (const float*)d_in[14]};
  const float* P[4] = {(const float*)d_in[6], (const float*)d_in[9],
                       (const float*)d_in[12], (const float*)d_in[15]};

  char* ws = (char*)d_ws;
  unsigned short* hbf = (unsigned short*)(ws + 0);
  unsigned short* Y[4] = {(unsigned short*)(ws + 1048576),
                          (unsigned short*)(ws + 2097152),
                          (unsigned short*)(ws + 2359296),
                          (unsigned short*)(ws + 2424832)};   // Y3: 512x32 padded
  float* CL = (float*)(ws + 2457600);
  float* stats = (float*)(ws + 2463744);
  float* part = (float*)(ws + 2480128);   // 4,292,608 B -> ends 6,772,736

  const unsigned long long WBF = 6772736ull;
  unsigned short* Wb[4] = {(unsigned short*)(ws + WBF),
                           (unsigned short*)(ws + WBF + 40960000ull),
                           (unsigned short*)(ws + WBF + 51200000ull),
                           (unsigned short*)(ws + WBF + 71680000ull)};  // W3 padded 32
  unsigned short* Pb[4] = {(unsigned short*)(ws + WBF + 76015040ull),
                           (unsigned short*)(ws + WBF + 78112192ull),
                           (unsigned short*)(ws + WBF + 78636480ull),
                           (unsigned short*)(ws + WBF + 78767552ull)};
  const bool BH = (ws_size >= WBF + 78800320ull);   // 85,573,056 B

  float* out = (float*)d_out;
  const int dims[4] = {1024, 256, 64, 16};
  const int nvoc[4] = {20000, 20000, 160000, 67735};
  const int colOff[4] = {0, 20000, 40000, 200000};
  const int nch[4] = {79, 79, 625, 265};
  const long long poffF[4] = {0, 80896, 161792, 801792};

  convert_h_kernel<<<512, 256, 0, stream>>>(hidden, hbf);

  if (BH) {
    CvtDesc d;
    const float* srcs[7] = {W[0], W[1], W[2], P[0], P[1], P[2], P[3]};
    unsigned short* dsts[7] = {Wb[0], Wb[1], Wb[2], Pb[0], Pb[1], Pb[2], Pb[3]};
    const int n4s[7] = {5120000, 1280000, 2560000, 262144, 65536, 16384, 4096};
    const int blk0s[8] = {0, 5000, 6250, 8750, 9006, 9070, 9086, 9090};
    for (int i = 0; i < 7; ++i) { d.src[i] = srcs[i]; d.dst[i] = dsts[i]; d.n4[i] = n4s[i]; }
    for (int i = 0; i < 8; ++i) d.blk0[i] = blk0s[i];
    convert_w_kernel<<<9090, 256, 0, stream>>>(d);
    convert_w3_kernel<<<1059, 256, 0, stream>>>(W[3], Wb[3]);

    // projections: Y_i = hbf * Pb_i^T (Y3 stored 32-wide, zero-padded)
    for (int i = 0; i < 4; ++i) {
      dim3 g(8, (dims[i] + 255) / 256);
      gemm_reg_kernel<false><<<g, 256, 0, stream>>>(
          hbf, 1024, 1024, Pb[i], 1024, nullptr, dims[i],
          nullptr, 0, Y[i], (i == 3 ? 32 : dims[i]), nullptr, 0);
    }
    cluster_kernel<<<512, 192, 0, stream>>>(Y[0], CW, CB, CL);

    // logits: buckets 0,1 (K=1024/256) m-tiled grid; 2,3 (K<=64) B-resident
    for (int i = 0; i < 2; ++i) {
      dim3 g(8, nch[i]);
      gemm_reg_kernel<true><<<g, 256, 0, stream>>>(
          Y[i], dims[i], dims[i], Wb[i], dims[i], Bb[i], nvoc[i],
          out + colOff[i], 267735LL, nullptr, 0, part + poffF[i], nch[i]);
    }
    gemm_reg_mloop_kernel<2><<<625, 256, 0, stream>>>(
        Y[2], 64, Wb[2], 64, Bb[2], 160000,
        out + 40000, 267735LL, part + poffF[2], 625);
    gemm_reg_mloop_kernel<1><<<265, 256, 0, stream>>>(
        Y[3], 32, Wb[3], 32, Bb[3], 67735,
        out + 200000, 267735LL, part + poffF[3], 265);
  } else {
    for (int i = 0; i < 4; ++i) {
      dim3 g(8, (dims[i] + 255) / 256);
      gemm_bt_kernel<false><<<g, 256, 0, stream>>>(
          hbf, 1024, 1024, P[i], nullptr, dims[i],
          nullptr, 0, Y[i], dims[i], nullptr, 0);
    }
    cluster_kernel<<<512, 192, 0, stream>>>(Y[0], CW, CB, CL);
    for (int i = 0; i < 4; ++i) {
      dim3 g(8, nch[i]);
      gemm_bt_kernel<true><<<g, 256, 0, stream>>>(
          Y[i], dims[i], dims[i], W[i], Bb[i], nvoc[i],
          out + colOff[i], 267735LL, nullptr, 0, part + poffF[i], nch[i]);
    }
  }

  reduce_stats_kernel<<<512 * 4, 128, 0, stream>>>(part, CL, stats);
  dim3 gn(512, 66);
  normalize_kernel<<<gn, 256, 0, stream>>>(out, stats, CL);
  loss_kernel<<<1, 512, 0, stream>>>(out, target, out + 137080320LL);
}

// Round 6
// 1180.330 us; speedup vs baseline: 1.8377x; 1.1168x over previous
//
#include <hip/hip_runtime.h>

// ---------------------------------------------------------------------------
// Adaptive softmax (TransformerXL style), MI355X/gfx950.
// R=512 rows, buckets: n={20000,20000,160000,67735}, d={1024,256,64,16}.
// Pipeline: h->bf16 | W,P->bf16 (one-time, W3 zero-padded K16->32) |
// Y_i = h P_i^T (reg MFMA) | cluster logits | pass1 logits: buckets 0,1 write
// raw fp32 + partials, buckets 2,3 partials ONLY (no store) | reduce stats |
// pass3: buckets 2,3 recompute + store normalized directly | normalize RMW
// (cols < 40000 only) | loss gather.
// Rationale: buckets 2,3 have huge output (327/139 MB) and tiny K (64/32) ->
// recompute is cheaper than write+RMW (1x output bytes instead of 3x).
// ---------------------------------------------------------------------------

typedef __bf16 bf16x8 __attribute__((ext_vector_type(8)));
typedef float  f32x4  __attribute__((ext_vector_type(4)));

#define NEG_HUGE (-3.402823466e38f)

__device__ __forceinline__ unsigned short f2bf(float x) {
  unsigned int u = __float_as_uint(x);
  u = (u + 0x7fffu + ((u >> 16) & 1u)) >> 16;   // RNE
  return (unsigned short)u;
}
__device__ __forceinline__ float bf2f(unsigned short h) {
  return __uint_as_float(((unsigned int)h) << 16);
}
// merge two (max, sumexp) pairs; NEG_HUGE sentinel keeps this NaN-free
__device__ __forceinline__ void mergeMS(float& m, float& s, float mo, float so) {
  float mn = fmaxf(m, mo);
  s = s * __expf(m - mn) + so * __expf(mo - mn);
  m = mn;
}

// ---------------------------------------------------------------- h -> bf16
__global__ __launch_bounds__(256) void convert_h_kernel(
    const float* __restrict__ h, unsigned short* __restrict__ o) {
  int i = (blockIdx.x * 256 + threadIdx.x) * 4;          // 512 blocks, exact
  float4 v = *reinterpret_cast<const float4*>(h + i);
  uint2 u;
  u.x = (unsigned int)f2bf(v.x) | ((unsigned int)f2bf(v.y) << 16);
  u.y = (unsigned int)f2bf(v.z) | ((unsigned int)f2bf(v.w) << 16);
  *reinterpret_cast<uint2*>(o + i) = u;
}

// ------------------------------------------------ W/P -> bf16 (one launch)
// 7 segments (W0..W2, P0..P3); W3 handled by convert_w3_kernel (padded).
struct CvtDesc {
  const float* src[7];
  unsigned short* dst[7];
  int n4[7];     // float4 count per segment
  int blk0[8];   // cumulative block offsets
};

__global__ __launch_bounds__(256) void convert_w_kernel(CvtDesc d) {
  int b = blockIdx.x, seg = 0;
  while (seg < 6 && b >= d.blk0[seg + 1]) ++seg;
  const float* __restrict__ s = d.src[seg];
  unsigned short* __restrict__ o = d.dst[seg];
  const int n4 = d.n4[seg];
  int base = (b - d.blk0[seg]) * 1024 + threadIdx.x;
#pragma unroll
  for (int i = 0; i < 4; ++i) {
    int v = base + i * 256;
    if (v < n4) {
      float4 x = reinterpret_cast<const float4*>(s)[v];
      uint2 u;
      u.x = (unsigned int)f2bf(x.x) | ((unsigned int)f2bf(x.y) << 16);
      u.y = (unsigned int)f2bf(x.z) | ((unsigned int)f2bf(x.w) << 16);
      reinterpret_cast<uint2*>(o)[v] = u;
    }
  }
}

// W3 [67735,16] fp32 -> bf16 padded to [67735,32] (cols 16..31 zero).
__global__ __launch_bounds__(256) void convert_w3_kernel(
    const float* __restrict__ s, unsigned short* __restrict__ o) {
  int t = blockIdx.x * 256 + threadIdx.x;
  int row = t >> 2, j = t & 3;
  if (row >= 67735) return;
  uint4 u = make_uint4(0u, 0u, 0u, 0u);
  if (j < 2) {
    float4 a = reinterpret_cast<const float4*>(s)[row * 4 + j * 2];
    float4 b = reinterpret_cast<const float4*>(s)[row * 4 + j * 2 + 1];
    u.x = (unsigned int)f2bf(a.x) | ((unsigned int)f2bf(a.y) << 16);
    u.y = (unsigned int)f2bf(a.z) | ((unsigned int)f2bf(a.w) << 16);
    u.z = (unsigned int)f2bf(b.x) | ((unsigned int)f2bf(b.y) << 16);
    u.w = (unsigned int)f2bf(b.z) | ((unsigned int)f2bf(b.w) << 16);
  }
  reinterpret_cast<uint4*>(o)[row * 4 + j] = u;
}

// -------------------------------------------- register GEMM (no LDS, bf16 B)
// C[512, N] = A_bf16[512, K] * B_bf16[N, K]^T (+bias). 64x256 per block.
template <bool SOFTMAX>
__global__ __launch_bounds__(256) void gemm_reg_kernel(
    const unsigned short* __restrict__ A, int lda, int K,
    const unsigned short* __restrict__ Bh, int ldb,
    const float* __restrict__ bias, int N,
    float* __restrict__ outF, long long ldo,
    unsigned short* __restrict__ outH, int ldh,
    float* __restrict__ partials, int nChunks) {
  __shared__ float red[64][4][2];
  const int tid = threadIdx.x;
  const int lane = tid & 63, w = tid >> 6;
  const int q = lane >> 4, l15 = lane & 15;
  const int row0 = blockIdx.x * 64;
  const int colBase = blockIdx.y * 256;

  const char* Ac = (const char*)A;
  const char* Bc = (const char*)Bh;
  int colg[4];
  unsigned aoff[4], boff[4];
#pragma unroll
  for (int nb = 0; nb < 4; ++nb) {
    colg[nb] = colBase + w * 64 + nb * 16 + l15;
    int cl = colg[nb] < N ? colg[nb] : N - 1;
    boff[nb] = (unsigned)((cl * ldb + q * 8) * 2);
  }
#pragma unroll
  for (int mb = 0; mb < 4; ++mb)
    aoff[mb] = (unsigned)(((row0 + mb * 16 + l15) * lda + q * 8) * 2);

  f32x4 acc[4][4];
#pragma unroll
  for (int i = 0; i < 4; ++i)
#pragma unroll
    for (int j = 0; j < 4; ++j) acc[i][j] = (f32x4){0.f, 0.f, 0.f, 0.f};

  for (int k = 0; k < K; k += 32) {
    bf16x8 fa[4], fb[4];
#pragma unroll
    for (int mb = 0; mb < 4; ++mb)
      fa[mb] = *reinterpret_cast<const bf16x8*>(Ac + aoff[mb] + 2 * k);
#pragma unroll
    for (int nb = 0; nb < 4; ++nb)
      fb[nb] = *reinterpret_cast<const bf16x8*>(Bc + boff[nb] + 2 * k);
#pragma unroll
    for (int mb = 0; mb < 4; ++mb)
#pragma unroll
      for (int nb = 0; nb < 4; ++nb)
        acc[mb][nb] = __builtin_amdgcn_mfma_f32_16x16x32_bf16(
            fa[mb], fb[nb], acc[mb][nb], 0, 0, 0);
  }

  if (SOFTMAX) {
    float bv[4];
#pragma unroll
    for (int nb = 0; nb < 4; ++nb) bv[nb] = (colg[nb] < N) ? bias[colg[nb]] : 0.f;
#pragma unroll
    for (int mb = 0; mb < 4; ++mb)
#pragma unroll
      for (int nb = 0; nb < 4; ++nb)
#pragma unroll
        for (int r = 0; r < 4; ++r) acc[mb][nb][r] += bv[nb];
#pragma unroll
    for (int mb = 0; mb < 4; ++mb)
#pragma unroll
      for (int nb = 0; nb < 4; ++nb)
        if (colg[nb] < N) {
#pragma unroll
          for (int r = 0; r < 4; ++r) {
            int rowg = row0 + mb * 16 + q * 4 + r;
            outF[(size_t)rowg * ldo + colg[nb]] = acc[mb][nb][r];
          }
        }
#pragma unroll
    for (int mb = 0; mb < 4; ++mb) {
#pragma unroll
      for (int r = 0; r < 4; ++r) {
        float mx = NEG_HUGE, s = 0.f;
#pragma unroll
        for (int nb = 0; nb < 4; ++nb)
          if (colg[nb] < N) mx = fmaxf(mx, acc[mb][nb][r]);
#pragma unroll
        for (int nb = 0; nb < 4; ++nb)
          if (colg[nb] < N) s += __expf(acc[mb][nb][r] - mx);
        for (int off = 1; off < 16; off <<= 1) {   // reduce over quad's 16 lanes
          float mo = __shfl_xor(mx, off);
          float so = __shfl_xor(s, off);
          mergeMS(mx, s, mo, so);
        }
        if (l15 == 0) {
          red[mb * 16 + q * 4 + r][w][0] = mx;
          red[mb * 16 + q * 4 + r][w][1] = s;
        }
      }
    }
    __syncthreads();
    if (tid < 64) {
      float m = red[tid][0][0], s = red[tid][0][1];
#pragma unroll
      for (int ww = 1; ww < 4; ++ww) mergeMS(m, s, red[tid][ww][0], red[tid][ww][1]);
      size_t pi = ((size_t)(row0 + tid) * nChunks + blockIdx.y) * 2;
      partials[pi] = m;
      partials[pi + 1] = s;
    }
  } else {
    // ldh may exceed N (padded store width); pad cols get zeros
#pragma unroll
    for (int mb = 0; mb < 4; ++mb)
#pragma unroll
      for (int nb = 0; nb < 4; ++nb)
        if (colg[nb] < ldh) {
#pragma unroll
          for (int r = 0; r < 4; ++r) {
            int rowg = row0 + mb * 16 + q * 4 + r;
            outH[(size_t)rowg * ldh + colg[nb]] =
                (colg[nb] < N) ? f2bf(acc[mb][nb][r]) : (unsigned short)0;
          }
        }
  }
}

// ------------------- register GEMM, B-in-registers, m-loop (K = KS*32 <= 64)
// One block per 256-col chunk; B fragments loaded ONCE, all 8 m-tiles looped.
// MODE 2: softmax partials ONLY (no logit store).
// MODE 3: recompute logits, store normalized: acc + bias - sub[row].
template <int KS, int MODE>
__global__ __launch_bounds__(256) void gemm_reg_mloop_kernel(
    const unsigned short* __restrict__ A, int lda,
    const unsigned short* __restrict__ Bh, int ldb,
    const float* __restrict__ bias, int N,
    float* __restrict__ outF, long long ldo,
    float* __restrict__ partials, int nChunks,
    const float* __restrict__ stats, const float* __restrict__ CL, int bucket) {
  __shared__ float red[64][4][2];
  __shared__ float subs[64];
  const int tid = threadIdx.x;
  const int lane = tid & 63, w = tid >> 6;
  const int q = lane >> 4, l15 = lane & 15;
  const int colBase = blockIdx.x * 256;

  const char* Ac = (const char*)A;
  const char* Bc = (const char*)Bh;
  int colg[4];
  float bv[4];
  bf16x8 fbr[KS][4];
#pragma unroll
  for (int nb = 0; nb < 4; ++nb) {
    colg[nb] = colBase + w * 64 + nb * 16 + l15;
    int cl = colg[nb] < N ? colg[nb] : N - 1;
    bv[nb] = (colg[nb] < N) ? bias[colg[nb]] : 0.f;
#pragma unroll
    for (int s = 0; s < KS; ++s)
      fbr[s][nb] = *reinterpret_cast<const bf16x8*>(
          Bc + (size_t)((cl * ldb + s * 32 + q * 8) * 2));
  }

  for (int m = 0; m < 8; ++m) {
    const int row0 = m * 64;
    if (MODE == 3) {
      if (tid < 64) {
        int row = row0 + tid;
        float s0 = stats[row * 8] + stats[row * 8 + 1];
        subs[tid] = stats[(row * 4 + bucket) * 2] + stats[(row * 4 + bucket) * 2 + 1]
                    - (CL[row * 3 + (bucket - 1)] - s0);
      }
      __syncthreads();
    }
    f32x4 acc[4][4];
#pragma unroll
    for (int i = 0; i < 4; ++i)
#pragma unroll
      for (int j = 0; j < 4; ++j) acc[i][j] = (f32x4){0.f, 0.f, 0.f, 0.f};
#pragma unroll
    for (int s = 0; s < KS; ++s) {
      bf16x8 fa[4];
#pragma unroll
      for (int mb = 0; mb < 4; ++mb)
        fa[mb] = *reinterpret_cast<const bf16x8*>(
            Ac + (size_t)(((row0 + mb * 16 + l15) * lda + s * 32 + q * 8) * 2));
#pragma unroll
      for (int mb = 0; mb < 4; ++mb)
#pragma unroll
        for (int nb = 0; nb < 4; ++nb)
          acc[mb][nb] = __builtin_amdgcn_mfma_f32_16x16x32_bf16(
              fa[mb], fbr[s][nb], acc[mb][nb], 0, 0, 0);
    }
#pragma unroll
    for (int mb = 0; mb < 4; ++mb)
#pragma unroll
      for (int nb = 0; nb < 4; ++nb)
#pragma unroll
        for (int r = 0; r < 4; ++r) acc[mb][nb][r] += bv[nb];

    if (MODE == 3) {
#pragma unroll
      for (int mb = 0; mb < 4; ++mb)
#pragma unroll
        for (int nb = 0; nb < 4; ++nb)
          if (colg[nb] < N) {
#pragma unroll
            for (int r = 0; r < 4; ++r) {
              int rl = mb * 16 + q * 4 + r;
              outF[(size_t)(row0 + rl) * ldo + colg[nb]] = acc[mb][nb][r] - subs[rl];
            }
          }
      __syncthreads();   // subs reused next m-iter
    } else {
#pragma unroll
      for (int mb = 0; mb < 4; ++mb) {
#pragma unroll
        for (int r = 0; r < 4; ++r) {
          float mx = NEG_HUGE, s = 0.f;
#pragma unroll
          for (int nb = 0; nb < 4; ++nb)
            if (colg[nb] < N) mx = fmaxf(mx, acc[mb][nb][r]);
#pragma unroll
          for (int nb = 0; nb < 4; ++nb)
            if (colg[nb] < N) s += __expf(acc[mb][nb][r] - mx);
          for (int off = 1; off < 16; off <<= 1) {
            float mo = __shfl_xor(mx, off);
            float so = __shfl_xor(s, off);
            mergeMS(mx, s, mo, so);
          }
          if (l15 == 0) {
            red[mb * 16 + q * 4 + r][w][0] = mx;
            red[mb * 16 + q * 4 + r][w][1] = s;
          }
        }
      }
      __syncthreads();
      if (tid < 64) {
        float mm = red[tid][0][0], s = red[tid][0][1];
#pragma unroll
        for (int ww = 1; ww < 4; ++ww) mergeMS(mm, s, red[tid][ww][0], red[tid][ww][1]);
        size_t pi = ((size_t)(row0 + tid) * nChunks + blockIdx.x) * 2;
        partials[pi] = mm;
        partials[pi + 1] = s;
      }
      __syncthreads();   // red reused next m-iter
    }
  }
}

// ------------------------------------------------ fallback GEMM (fp32 B, LDS)
constexpr int GBM = 64, GBN = 256, GBK = 64, GPK = GBK + 8;

template <bool SOFTMAX>
__global__ __launch_bounds__(256) void gemm_bt_kernel(
    const unsigned short* __restrict__ A, int lda, int K,
    const float* __restrict__ B, const float* __restrict__ bias, int N,
    float* __restrict__ outF, long long ldo,
    unsigned short* __restrict__ outH, int ldh,
    float* __restrict__ partials, int nChunks) {
  __shared__ unsigned short As[GBM][GPK];
  __shared__ unsigned short Bs[GBN][GPK];
  __shared__ float red[GBM][4][2];

  const int tid = threadIdx.x;
  const int lane = tid & 63, w = tid >> 6;
  const int q = lane >> 4, l15 = lane & 15;
  const int row0 = blockIdx.x * GBM;
  const int colBase = blockIdx.y * GBN;

  f32x4 acc[4][4];
#pragma unroll
  for (int i = 0; i < 4; ++i)
#pragma unroll
    for (int j = 0; j < 4; ++j) acc[i][j] = (f32x4){0.f, 0.f, 0.f, 0.f};

  for (int k0 = 0; k0 < K; k0 += GBK) {
    __syncthreads();
#pragma unroll
    for (int i = 0; i < 2; ++i) {
      int f = i * 2048 + tid * 8;
      int r = f >> 6, kk = f & 63;
      uint4 va = make_uint4(0u, 0u, 0u, 0u);
      if (k0 + kk < K)
        va = *reinterpret_cast<const uint4*>(A + (size_t)(row0 + r) * lda + k0 + kk);
      *reinterpret_cast<uint4*>(&As[r][kk]) = va;
    }
#pragma unroll
    for (int i = 0; i < 16; ++i) {
      int f = i * 1024 + tid * 4;
      int c = f >> 6, kk = f & 63;
      int col = colBase + c;
      float4 v = make_float4(0.f, 0.f, 0.f, 0.f);
      if (col < N && k0 + kk < K)
        v = *reinterpret_cast<const float4*>(B + (size_t)col * K + k0 + kk);
      uint2 u;
      u.x = (unsigned int)f2bf(v.x) | ((unsigned int)f2bf(v.y) << 16);
      u.y = (unsigned int)f2bf(v.z) | ((unsigned int)f2bf(v.w) << 16);
      *reinterpret_cast<uint2*>(&Bs[c][kk]) = u;
    }
    __syncthreads();
#pragma unroll
    for (int ks = 0; ks < GBK; ks += 32) {
      bf16x8 fa[4], fb[4];
#pragma unroll
      for (int mb = 0; mb < 4; ++mb)
        fa[mb] = *reinterpret_cast<const bf16x8*>(&As[mb * 16 + l15][ks + q * 8]);
#pragma unroll
      for (int nb = 0; nb < 4; ++nb)
        fb[nb] = *reinterpret_cast<const bf16x8*>(&Bs[w * 64 + nb * 16 + l15][ks + q * 8]);
#pragma unroll
      for (int mb = 0; mb < 4; ++mb)
#pragma unroll
        for (int nb = 0; nb < 4; ++nb)
          acc[mb][nb] = __builtin_amdgcn_mfma_f32_16x16x32_bf16(
              fa[mb], fb[nb], acc[mb][nb], 0, 0, 0);
    }
  }

  int colg[4];
#pragma unroll
  for (int nb = 0; nb < 4; ++nb) colg[nb] = colBase + w * 64 + nb * 16 + l15;

  if (SOFTMAX) {
    float bv[4];
#pragma unroll
    for (int nb = 0; nb < 4; ++nb) bv[nb] = (colg[nb] < N) ? bias[colg[nb]] : 0.f;
#pragma unroll
    for (int mb = 0; mb < 4; ++mb)
#pragma unroll
      for (int nb = 0; nb < 4; ++nb)
#pragma unroll
        for (int r = 0; r < 4; ++r) acc[mb][nb][r] += bv[nb];
#pragma unroll
    for (int mb = 0; mb < 4; ++mb)
#pragma unroll
      for (int nb = 0; nb < 4; ++nb)
        if (colg[nb] < N) {
#pragma unroll
          for (int r = 0; r < 4; ++r) {
            int rowg = row0 + mb * 16 + q * 4 + r;
            outF[(size_t)rowg * ldo + colg[nb]] = acc[mb][nb][r];
          }
        }
#pragma unroll
    for (int mb = 0; mb < 4; ++mb) {
#pragma unroll
      for (int r = 0; r < 4; ++r) {
        float mx = NEG_HUGE, s = 0.f;
#pragma unroll
        for (int nb = 0; nb < 4; ++nb)
          if (colg[nb] < N) mx = fmaxf(mx, acc[mb][nb][r]);
#pragma unroll
        for (int nb = 0; nb < 4; ++nb)
          if (colg[nb] < N) s += __expf(acc[mb][nb][r] - mx);
        for (int off = 1; off < 16; off <<= 1) {
          float mo = __shfl_xor(mx, off);
          float so = __shfl_xor(s, off);
          mergeMS(mx, s, mo, so);
        }
        if (l15 == 0) {
          red[mb * 16 + q * 4 + r][w][0] = mx;
          red[mb * 16 + q * 4 + r][w][1] = s;
        }
      }
    }
    __syncthreads();
    if (tid < 64) {
      float m = red[tid][0][0], s = red[tid][0][1];
#pragma unroll
      for (int ww = 1; ww < 4; ++ww) mergeMS(m, s, red[tid][ww][0], red[tid][ww][1]);
      size_t pi = ((size_t)(row0 + tid) * nChunks + blockIdx.y) * 2;
      partials[pi] = m;
      partials[pi + 1] = s;
    }
  } else {
#pragma unroll
    for (int mb = 0; mb < 4; ++mb)
#pragma unroll
      for (int nb = 0; nb < 4; ++nb)
        if (colg[nb] < N) {
#pragma unroll
          for (int r = 0; r < 4; ++r) {
            int rowg = row0 + mb * 16 + q * 4 + r;
            outH[(size_t)rowg * ldh + colg[nb]] = f2bf(acc[mb][nb][r]);
          }
        }
  }
}

// ------------------------------------------------- cluster logits [512 x 3]
__global__ __launch_bounds__(192) void cluster_kernel(
    const unsigned short* __restrict__ Y0, const float* __restrict__ CW,
    const float* __restrict__ CB, float* __restrict__ CL) {
  int row = blockIdx.x;
  int w = threadIdx.x >> 6, lane = threadIdx.x & 63;
  float s = 0.f;
  for (int k = lane; k < 1024; k += 64)
    s += bf2f(Y0[row * 1024 + k]) * CW[w * 1024 + k];
  for (int off = 32; off > 0; off >>= 1) s += __shfl_xor(s, off);
  if (lane == 0) CL[row * 3 + w] = s + CB[w];
}

// ------------------------------------- reduce partials -> (m, log sumexp)
__global__ __launch_bounds__(128) void reduce_stats_kernel(
    const float* __restrict__ part, const float* __restrict__ CL,
    float* __restrict__ stats) {
  const int nch[4] = {79, 79, 625, 265};
  const long long poff[4] = {0, 80896, 161792, 801792};  // floats
  int row = blockIdx.x >> 2, b = blockIdx.x & 3;
  const float* p = part + poff[b] + (long long)row * nch[b] * 2;
  float m = NEG_HUGE, s = 0.f;
  for (int j = threadIdx.x; j < nch[b]; j += 128) mergeMS(m, s, p[j * 2], p[j * 2 + 1]);
  for (int off = 1; off < 64; off <<= 1) {
    float mo = __shfl_xor(m, off);
    float so = __shfl_xor(s, off);
    mergeMS(m, s, mo, so);
  }
  __shared__ float sm[2][2];
  int w = threadIdx.x >> 6;
  if ((threadIdx.x & 63) == 0) { sm[w][0] = m; sm[w][1] = s; }
  __syncthreads();
  if (threadIdx.x == 0) {
    mergeMS(m, s, sm[1][0], sm[1][1]);
    if (b == 0)  // head softmax includes the 3 cluster logits
      for (int c = 0; c < 3; ++c) mergeMS(m, s, CL[row * 3 + c], 1.f);
    stats[(row * 4 + b) * 2] = m;
    stats[(row * 4 + b) * 2 + 1] = logf(s);
  }
}

// ------------------------------------------------------------- normalize
// RMW over cols [0, maxcol) of each row. Fast path: maxcol=40000 (buckets
// 0,1 only; buckets 2,3 written normalized by pass-3 GEMM). Fallback: 267735.
__global__ __launch_bounds__(256) void normalize_kernel(
    float* __restrict__ out, const float* __restrict__ stats,
    const float* __restrict__ CL, int maxcol) {
  const int row = blockIdx.x;
  const float s0 = stats[row * 8 + 0] + stats[row * 8 + 1];        // m0 + L0
  const float s1 = stats[(row * 4 + 1) * 2] + stats[(row * 4 + 1) * 2 + 1]
                   - (CL[row * 3 + 0] - s0);
  const float s2 = stats[(row * 4 + 2) * 2] + stats[(row * 4 + 2) * 2 + 1]
                   - (CL[row * 3 + 1] - s0);
  const float s3 = stats[(row * 4 + 3) * 2] + stats[(row * 4 + 3) * 2 + 1]
                   - (CL[row * 3 + 2] - s0);
  float* op = out + (size_t)row * 267735LL;
  const int lead = row & 3;        // (row*267735)%4 == (row*3)%4
  const int NV = (maxcol - lead) >> 2;
  float4* vp = reinterpret_cast<float4*>(op + lead);

  int vbase = blockIdx.y * 1024 + threadIdx.x;
#pragma unroll
  for (int i = 0; i < 4; ++i) {
    int v = vbase + i * 256;
    if (v < NV) {
      float4 x = vp[v];
      int c0 = lead + v * 4;
      x.x -= (c0     < 20000) ? s0 : (c0     < 40000) ? s1 : (c0     < 200000) ? s2 : s3;
      x.y -= (c0 + 1 < 20000) ? s0 : (c0 + 1 < 40000) ? s1 : (c0 + 1 < 200000) ? s2 : s3;
      x.z -= (c0 + 2 < 20000) ? s0 : (c0 + 2 < 40000) ? s1 : (c0 + 2 < 200000) ? s2 : s3;
      x.w -= (c0 + 3 < 20000) ? s0 : (c0 + 3 < 40000) ? s1 : (c0 + 3 < 200000) ? s2 : s3;
      vp[v] = x;
    }
  }
  if (blockIdx.y == 0 && threadIdx.x == 0) {
    for (int c = 0; c < lead; ++c) op[c] -= s0;                  // head, bucket 0
    for (int c = lead + NV * 4; c < maxcol; ++c)                 // tail
      op[c] -= (c < 20000) ? s0 : (c < 40000) ? s1 : (c < 200000) ? s2 : s3;
  }
}

// ------------------------------------------------------------------ loss
__global__ __launch_bounds__(512) void loss_kernel(
    const float* __restrict__ out, const int* __restrict__ target,
    float* __restrict__ lossOut) {
  __shared__ float sm[512];
  int t = threadIdx.x;
  sm[t] = out[(size_t)t * 267735 + target[t]];  // final lp at target col
  __syncthreads();
  for (int s = 256; s > 0; s >>= 1) {
    if (t < s) sm[t] += sm[t + s];
    __syncthreads();
  }
  if (t == 0) lossOut[0] = -sm[0] / 512.f;
}

// ---------------------------------------------------------------------------
extern "C" void kernel_launch(void* const* d_in, const int* in_sizes, int n_in,
                              void* d_out, int out_size, void* d_ws, size_t ws_size,
                              hipStream_t stream) {
  const float* hidden = (const float*)d_in[0];
  const int* target = (const int*)d_in[1];
  const float* CW = (const float*)d_in[2];
  const float* CB = (const float*)d_in[3];
  const float* W[4] = {(const float*)d_in[4], (const float*)d_in[7],
                       (const float*)d_in[10], (const float*)d_in[13]};
  const float* Bb[4] = {(const float*)d_in[5], (const float*)d_in[8],
                        (const float*)d_in[11], (const float*)d_in[14]};
  const float* P[4] = {(const float*)d_in[6], (const float*)d_in[9],
                       (const float*)d_in[12], (const float*)d_in[15]};

  char* ws = (char*)d_ws;
  unsigned short* hbf = (unsigned short*)(ws + 0);
  unsigned short* Y[4] = {(unsigned short*)(ws + 1048576),
                          (unsigned short*)(ws + 2097152),
                          (unsigned short*)(ws + 2359296),
                          (unsigned short*)(ws + 2424832)};   // Y3: 512x32 padded
  float* CL = (float*)(ws + 2457600);
  float* stats = (float*)(ws + 2463744);
  float* part = (float*)(ws + 2480128);   // 4,292,608 B -> ends 6,772,736

  const unsigned long long WBF = 6772736ull;
  unsigned short* Wb[4] = {(unsigned short*)(ws + WBF),
                           (unsigned short*)(ws + WBF + 40960000ull),
                           (unsigned short*)(ws + WBF + 51200000ull),
                           (unsigned short*)(ws + WBF + 71680000ull)};  // W3 padded 32
  unsigned short* Pb[4] = {(unsigned short*)(ws + WBF + 76015040ull),
                           (unsigned short*)(ws + WBF + 78112192ull),
                           (unsigned short*)(ws + WBF + 78636480ull),
                           (unsigned short*)(ws + WBF + 78767552ull)};
  const bool BH = (ws_size >= WBF + 78800320ull);   // 85,573,056 B

  float* out = (float*)d_out;
  const int dims[4] = {1024, 256, 64, 16};
  const int nvoc[4] = {20000, 20000, 160000, 67735};
  const int colOff[4] = {0, 20000, 40000, 200000};
  const int nch[4] = {79, 79, 625, 265};
  const long long poffF[4] = {0, 80896, 161792, 801792};

  convert_h_kernel<<<512, 256, 0, stream>>>(hidden, hbf);

  if (BH) {
    CvtDesc d;
    const float* srcs[7] = {W[0], W[1], W[2], P[0], P[1], P[2], P[3]};
    unsigned short* dsts[7] = {Wb[0], Wb[1], Wb[2], Pb[0], Pb[1], Pb[2], Pb[3]};
    const int n4s[7] = {5120000, 1280000, 2560000, 262144, 65536, 16384, 4096};
    const int blk0s[8] = {0, 5000, 6250, 8750, 9006, 9070, 9086, 9090};
    for (int i = 0; i < 7; ++i) { d.src[i] = srcs[i]; d.dst[i] = dsts[i]; d.n4[i] = n4s[i]; }
    for (int i = 0; i < 8; ++i) d.blk0[i] = blk0s[i];
    convert_w_kernel<<<9090, 256, 0, stream>>>(d);
    convert_w3_kernel<<<1059, 256, 0, stream>>>(W[3], Wb[3]);

    // projections: Y_i = hbf * Pb_i^T (Y3 stored 32-wide, zero-padded)
    for (int i = 0; i < 4; ++i) {
      dim3 g(8, (dims[i] + 255) / 256);
      gemm_reg_kernel<false><<<g, 256, 0, stream>>>(
          hbf, 1024, 1024, Pb[i], 1024, nullptr, dims[i],
          nullptr, 0, Y[i], (i == 3 ? 32 : dims[i]), nullptr, 0);
    }
    cluster_kernel<<<512, 192, 0, stream>>>(Y[0], CW, CB, CL);

    // pass1: buckets 0,1 write raw logits + partials; 2,3 partials only
    for (int i = 0; i < 2; ++i) {
      dim3 g(8, nch[i]);
      gemm_reg_kernel<true><<<g, 256, 0, stream>>>(
          Y[i], dims[i], dims[i], Wb[i], dims[i], Bb[i], nvoc[i],
          out + colOff[i], 267735LL, nullptr, 0, part + poffF[i], nch[i]);
    }
    gemm_reg_mloop_kernel<2, 2><<<625, 256, 0, stream>>>(
        Y[2], 64, Wb[2], 64, Bb[2], 160000,
        nullptr, 0, part + poffF[2], 625, nullptr, nullptr, 2);
    gemm_reg_mloop_kernel<1, 2><<<265, 256, 0, stream>>>(
        Y[3], 32, Wb[3], 32, Bb[3], 67735,
        nullptr, 0, part + poffF[3], 265, nullptr, nullptr, 3);

    reduce_stats_kernel<<<512 * 4, 128, 0, stream>>>(part, CL, stats);

    // pass3: buckets 2,3 recompute + store normalized
    gemm_reg_mloop_kernel<2, 3><<<625, 256, 0, stream>>>(
        Y[2], 64, Wb[2], 64, Bb[2], 160000,
        out + 40000, 267735LL, nullptr, 625, stats, CL, 2);
    gemm_reg_mloop_kernel<1, 3><<<265, 256, 0, stream>>>(
        Y[3], 32, Wb[3], 32, Bb[3], 67735,
        out + 200000, 267735LL, nullptr, 265, stats, CL, 3);

    dim3 gn(512, 10);
    normalize_kernel<<<gn, 256, 0, stream>>>(out, stats, CL, 40000);
  } else {
    for (int i = 0; i < 4; ++i) {
      dim3 g(8, (dims[i] + 255) / 256);
      gemm_bt_kernel<false><<<g, 256, 0, stream>>>(
          hbf, 1024, 1024, P[i], nullptr, dims[i],
          nullptr, 0, Y[i], dims[i], nullptr, 0);
    }
    cluster_kernel<<<512, 192, 0, stream>>>(Y[0], CW, CB, CL);
    for (int i = 0; i < 4; ++i) {
      dim3 g(8, nch[i]);
      gemm_bt_kernel<true><<<g, 256, 0, stream>>>(
          Y[i], dims[i], dims[i], W[i], Bb[i], nvoc[i],
          out + colOff[i], 267735LL, nullptr, 0, part + poffF[i], nch[i]);
    }
    reduce_stats_kernel<<<512 * 4, 128, 0, stream>>>(part, CL, stats);
    dim3 gn(512, 66);
    normalize_kernel<<<gn, 256, 0, stream>>>(out, stats, CL, 267735);
  }

  loss_kernel<<<1, 512, 0, stream>>>(out, target, out + 137080320LL);
}